// Round 1
// baseline (307.811 us; speedup 1.0000x reference)
//
#include <hip/hip_runtime.h>
#include <hip/hip_bf16.h>

#define EMB 1024
#define NEXP 8
#define NH 1024
#define N_GU 2048
#define TOPK 2

#define BM 128
#define BN 128
#define BK 32
#define LDK 40
#define MAXTILES 72

typedef __attribute__((ext_vector_type(4))) float f32x4;
typedef __attribute__((ext_vector_type(8))) short s16x8;
typedef __attribute__((ext_vector_type(4))) short s16x4;

__device__ __forceinline__ unsigned short f2bf(float f) {
  union { float f; unsigned int u; } a; a.f = f;
  unsigned int u = a.u;
  unsigned int r = (u + 0x7FFFu + ((u >> 16) & 1u)) >> 16;
  return (unsigned short)r;
}

// ---------------- fp32 -> bf16 conversion ----------------
__global__ void convert_bf16(const float* __restrict__ in, unsigned short* __restrict__ out, int n4) {
  int i = blockIdx.x * blockDim.x + threadIdx.x;
  if (i >= n4) return;
  float4 v = ((const float4*)in)[i];
  s16x4 o;
  o[0] = (short)f2bf(v.x);
  o[1] = (short)f2bf(v.y);
  o[2] = (short)f2bf(v.z);
  o[3] = (short)f2bf(v.w);
  ((s16x4*)out)[i] = o;
}

// ---------------- router: scores, top-2, softmax ----------------
__global__ void router_topk(const float* __restrict__ x, const float* __restrict__ rw,
                            const float* __restrict__ rb, int T,
                            int* __restrict__ tokE, float* __restrict__ tokW,
                            int* __restrict__ counts) {
  int gwid = (blockIdx.x * blockDim.x + threadIdx.x) >> 6;
  int lane = threadIdx.x & 63;
  if (gwid >= T) return;
  const float* h = x + (size_t)gwid * EMB;
  float hreg[16];
  #pragma unroll
  for (int i = 0; i < 16; ++i) hreg[i] = h[lane + 64 * i];
  float sc[NEXP];
  #pragma unroll
  for (int e = 0; e < NEXP; ++e) {
    const float* w = rw + e * EMB;
    float s = 0.f;
    #pragma unroll
    for (int i = 0; i < 16; ++i) s += hreg[i] * w[lane + 64 * i];
    #pragma unroll
    for (int off = 32; off > 0; off >>= 1) s += __shfl_xor(s, off);
    sc[e] = s + rb[e];
  }
  if (lane == 0) {
    int e0 = 0; float v0 = sc[0];
    #pragma unroll
    for (int e = 1; e < NEXP; ++e) if (sc[e] > v0) { v0 = sc[e]; e0 = e; }
    int e1 = -1; float v1 = -3.0e38f;
    #pragma unroll
    for (int e = 0; e < NEXP; ++e) { if (e == e0) continue; if (sc[e] > v1) { v1 = sc[e]; e1 = e; } }
    float ex = __expf(v1 - v0);
    float w0 = 1.f / (1.f + ex);
    float w1 = ex / (1.f + ex);
    tokE[gwid * 2] = e0; tokE[gwid * 2 + 1] = e1;
    tokW[gwid * 2] = w0; tokW[gwid * 2 + 1] = w1;
    atomicAdd(&counts[e0], 1);
    atomicAdd(&counts[e1], 1);
  }
}

// ---------------- offsets + tile map ----------------
__global__ void build_meta(const int* __restrict__ counts, int* __restrict__ offsets,
                           int* __restrict__ tilemeta) {
  if (threadIdx.x == 0 && blockIdx.x == 0) {
    int off = 0, nt = 0;
    for (int e = 0; e < NEXP; ++e) {
      offsets[e] = off;
      int c = counts[e];
      int ntile = (c + BM - 1) / BM;
      for (int t = 0; t < ntile; ++t) {
        tilemeta[1 + nt * 3 + 0] = e;
        tilemeta[1 + nt * 3 + 1] = off + t * BM;
        tilemeta[1 + nt * 3 + 2] = off + c;
        nt++;
      }
      off += c;
    }
    offsets[NEXP] = off;
    tilemeta[0] = nt;
  }
}

// ---------------- scatter assignments into expert-grouped order ----------------
__global__ void scatter_tokens(const int* __restrict__ tokE, const int* __restrict__ offsets,
                               int* __restrict__ fill, int* __restrict__ rows,
                               int* __restrict__ apos, int A) {
  int i = blockIdx.x * blockDim.x + threadIdx.x;
  if (i >= A) return;
  int e = tokE[i];
  int p = atomicAdd(&fill[e], 1) + offsets[e];
  rows[p] = i >> 1;   // token index
  apos[i] = p;
}

// ---------------- grouped GEMM 1: gathered x rows @ gate_up_w[e]^T, fused SwiGLU ----------------
__global__ __launch_bounds__(256) void gemm_gate_up(
    const unsigned short* __restrict__ xb,
    const unsigned short* __restrict__ gub,
    const float* __restrict__ gu_bias,
    const int* __restrict__ rows,
    const int* __restrict__ tilemeta,
    unsigned short* __restrict__ hact) {
  __shared__ __align__(16) short As[BM][LDK];
  __shared__ __align__(16) short Bs[BN][LDK];
  int nt = tilemeta[0];
  int tileid = blockIdx.x;
  if (tileid >= nt) return;
  int e    = tilemeta[1 + tileid * 3 + 0];
  int m0   = tilemeta[1 + tileid * 3 + 1];
  int mEnd = tilemeta[1 + tileid * 3 + 2];
  int n0   = blockIdx.y * BN;

  int t = threadIdx.x;
  int lane = t & 63;
  int wid = t >> 6;
  int wr = wid >> 1, wc = wid & 1;

  // staging: thread t loads row t>>1, 16 consecutive cols at (t&1)*16
  int srow = t >> 1;
  int scol = (t & 1) * 16;
  int aidx = m0 + srow; if (aidx >= mEnd) aidx = mEnd - 1;
  int atok = rows[aidx];
  const unsigned short* aptr = xb + (size_t)atok * EMB + scol;
  const unsigned short* bptr = gub + ((size_t)e * N_GU + (n0 + srow)) * EMB + scol;
  short* adst = &As[srow][scol];
  short* bdst = &Bs[srow][scol];

  int fr = lane & 15;
  int koff = (lane >> 4) * 8;

  f32x4 acc[4][4];
  #pragma unroll
  for (int i = 0; i < 4; ++i)
    #pragma unroll
    for (int j = 0; j < 4; ++j) acc[i][j] = (f32x4){0.f, 0.f, 0.f, 0.f};

  for (int k0 = 0; k0 < EMB; k0 += BK) {
    __syncthreads();
    *(s16x8*)adst       = *(const s16x8*)(aptr + k0);
    *(s16x8*)(adst + 8) = *(const s16x8*)(aptr + k0 + 8);
    *(s16x8*)bdst       = *(const s16x8*)(bptr + k0);
    *(s16x8*)(bdst + 8) = *(const s16x8*)(bptr + k0 + 8);
    __syncthreads();
    s16x8 a[4], b[4];
    #pragma unroll
    for (int i = 0; i < 4; ++i) a[i] = *(const s16x8*)&As[wr * 64 + i * 16 + fr][koff];
    #pragma unroll
    for (int j = 0; j < 4; ++j) b[j] = *(const s16x8*)&Bs[wc * 64 + j * 16 + fr][koff];
    #pragma unroll
    for (int i = 0; i < 4; ++i)
      #pragma unroll
      for (int j = 0; j < 4; ++j)
        acc[i][j] = __builtin_amdgcn_mfma_f32_16x16x32_bf16(a[i], b[j], acc[i][j], 0, 0, 0);
  }

  // epilogue: bias + SwiGLU (pair even/odd N columns via shfl_xor 1), write bf16 h_act
  const float* bias_e = gu_bias + (size_t)e * N_GU;
  int rbase = m0 + wr * 64 + ((lane >> 4) * 4);
  #pragma unroll
  for (int i = 0; i < 4; ++i) {
    #pragma unroll
    for (int j = 0; j < 4; ++j) {
      int n = n0 + wc * 64 + j * 16 + fr;
      float v[4], o[4];
      #pragma unroll
      for (int r = 0; r < 4; ++r) v[r] = acc[i][j][r] + bias_e[n];
      #pragma unroll
      for (int r = 0; r < 4; ++r) o[r] = __shfl_xor(v[r], 1);
      if ((lane & 1) == 0) {
        int outc = n >> 1;
        #pragma unroll
        for (int r = 0; r < 4; ++r) {
          int pos = rbase + i * 16 + r;
          if (pos < mEnd) {
            float g = v[r], u = o[r];
            float gc = fminf(fmaxf(g, -7.f), 7.f);
            float uc = fminf(fmaxf(u, -7.f), 7.f);
            float sig = 1.f / (1.f + __expf(-1.702f * g));
            float act = gc * sig * (uc + 1.f);
            hact[(size_t)pos * NH + outc] = f2bf(act);
          }
        }
      }
    }
  }
}

// ---------------- grouped GEMM 2: h_act @ down_w[e]^T ----------------
__global__ __launch_bounds__(256) void gemm_down(
    const unsigned short* __restrict__ hact,
    const unsigned short* __restrict__ dwb,
    const int* __restrict__ tilemeta,
    float* __restrict__ y) {
  __shared__ __align__(16) short As[BM][LDK];
  __shared__ __align__(16) short Bs[BN][LDK];
  int nt = tilemeta[0];
  int tileid = blockIdx.x;
  if (tileid >= nt) return;
  int e    = tilemeta[1 + tileid * 3 + 0];
  int m0   = tilemeta[1 + tileid * 3 + 1];
  int mEnd = tilemeta[1 + tileid * 3 + 2];
  int n0   = blockIdx.y * BN;

  int t = threadIdx.x;
  int lane = t & 63;
  int wid = t >> 6;
  int wr = wid >> 1, wc = wid & 1;

  int srow = t >> 1;
  int scol = (t & 1) * 16;
  int aidx = m0 + srow; if (aidx >= mEnd) aidx = mEnd - 1;
  const unsigned short* aptr = hact + (size_t)aidx * NH + scol;
  const unsigned short* bptr = dwb + ((size_t)e * EMB + (n0 + srow)) * NH + scol;
  short* adst = &As[srow][scol];
  short* bdst = &Bs[srow][scol];

  int fr = lane & 15;
  int koff = (lane >> 4) * 8;

  f32x4 acc[4][4];
  #pragma unroll
  for (int i = 0; i < 4; ++i)
    #pragma unroll
    for (int j = 0; j < 4; ++j) acc[i][j] = (f32x4){0.f, 0.f, 0.f, 0.f};

  for (int k0 = 0; k0 < NH; k0 += BK) {
    __syncthreads();
    *(s16x8*)adst       = *(const s16x8*)(aptr + k0);
    *(s16x8*)(adst + 8) = *(const s16x8*)(aptr + k0 + 8);
    *(s16x8*)bdst       = *(const s16x8*)(bptr + k0);
    *(s16x8*)(bdst + 8) = *(const s16x8*)(bptr + k0 + 8);
    __syncthreads();
    s16x8 a[4], b[4];
    #pragma unroll
    for (int i = 0; i < 4; ++i) a[i] = *(const s16x8*)&As[wr * 64 + i * 16 + fr][koff];
    #pragma unroll
    for (int j = 0; j < 4; ++j) b[j] = *(const s16x8*)&Bs[wc * 64 + j * 16 + fr][koff];
    #pragma unroll
    for (int i = 0; i < 4; ++i)
      #pragma unroll
      for (int j = 0; j < 4; ++j)
        acc[i][j] = __builtin_amdgcn_mfma_f32_16x16x32_bf16(a[i], b[j], acc[i][j], 0, 0, 0);
  }

  int rbase = m0 + wr * 64 + ((lane >> 4) * 4);
  #pragma unroll
  for (int i = 0; i < 4; ++i) {
    #pragma unroll
    for (int j = 0; j < 4; ++j) {
      int n = n0 + wc * 64 + j * 16 + fr;
      #pragma unroll
      for (int r = 0; r < 4; ++r) {
        int pos = rbase + i * 16 + r;
        if (pos < mEnd) y[(size_t)pos * EMB + n] = acc[i][j][r];
      }
    }
  }
}

// ---------------- final combine: weighted sum of the two expert outputs ----------------
__global__ void combine_out(const float* __restrict__ y, const float* __restrict__ down_b,
                            const int* __restrict__ tokE, const float* __restrict__ tokW,
                            const int* __restrict__ apos, float* __restrict__ out, int T) {
  int i = blockIdx.x * blockDim.x + threadIdx.x;
  int tot = T * (EMB / 4);
  if (i >= tot) return;
  int tok = i >> 8;          // EMB/4 = 256
  int c = i & 255;
  int e0 = tokE[tok * 2], e1 = tokE[tok * 2 + 1];
  float w0 = tokW[tok * 2], w1 = tokW[tok * 2 + 1];
  int p0 = apos[tok * 2], p1 = apos[tok * 2 + 1];
  float4 y0 = ((const float4*)(y + (size_t)p0 * EMB))[c];
  float4 y1 = ((const float4*)(y + (size_t)p1 * EMB))[c];
  float4 b0 = ((const float4*)(down_b + (size_t)e0 * EMB))[c];
  float4 b1 = ((const float4*)(down_b + (size_t)e1 * EMB))[c];
  float4 o;
  o.x = w0 * (y0.x + b0.x) + w1 * (y1.x + b1.x);
  o.y = w0 * (y0.y + b0.y) + w1 * (y1.y + b1.y);
  o.z = w0 * (y0.z + b0.z) + w1 * (y1.z + b1.z);
  o.w = w0 * (y0.w + b0.w) + w1 * (y1.w + b1.w);
  ((float4*)out)[i] = o;
}

extern "C" void kernel_launch(void* const* d_in, const int* in_sizes, int n_in,
                              void* d_out, int out_size, void* d_ws, size_t ws_size,
                              hipStream_t stream) {
  const float* x   = (const float*)d_in[0];
  const float* rw  = (const float*)d_in[1];
  const float* rb  = (const float*)d_in[2];
  const float* guw = (const float*)d_in[3];
  const float* gub = (const float*)d_in[4];
  const float* dw  = (const float*)d_in[5];
  const float* db  = (const float*)d_in[6];
  float* out = (float*)d_out;

  int T = in_sizes[0] / EMB;   // 4096
  int A = T * TOPK;            // 8192

  char* ws = (char*)d_ws;
  size_t off = 0;
  auto alloc = [&](size_t bytes) -> void* {
    void* p = ws + off;
    off = (off + bytes + 255) & ~((size_t)255);
    return p;
  };
  unsigned short* xb   = (unsigned short*)alloc((size_t)T * EMB * 2);
  unsigned short* guwb = (unsigned short*)alloc((size_t)NEXP * N_GU * EMB * 2);
  unsigned short* dwb  = (unsigned short*)alloc((size_t)NEXP * EMB * NH * 2);
  unsigned short* hact = (unsigned short*)alloc((size_t)A * NH * 2);
  float* y             = (float*)alloc((size_t)A * EMB * 4);
  int*   tokE    = (int*)alloc((size_t)A * 4);
  float* tokW    = (float*)alloc((size_t)A * 4);
  int*   apos    = (int*)alloc((size_t)A * 4);
  int*   rowsArr = (int*)alloc((size_t)A * 4);
  int*   counts  = (int*)alloc(NEXP * 4);
  int*   fill    = (int*)alloc(NEXP * 4);
  int*   offsets = (int*)alloc((NEXP + 1) * 4);
  int*   tilemeta= (int*)alloc((1 + MAXTILES * 3) * 4);

  hipMemsetAsync(counts, 0, NEXP * 4, stream);
  hipMemsetAsync(fill, 0, NEXP * 4, stream);

  int thr = 256;
  int n4x = T * EMB / 4;
  int n4g = NEXP * N_GU * EMB / 4;
  int n4d = NEXP * EMB * NH / 4;
  convert_bf16<<<(n4x + thr - 1) / thr, thr, 0, stream>>>(x, xb, n4x);
  convert_bf16<<<(n4g + thr - 1) / thr, thr, 0, stream>>>(guw, guwb, n4g);
  convert_bf16<<<(n4d + thr - 1) / thr, thr, 0, stream>>>(dw, dwb, n4d);

  router_topk<<<T / 4, 256, 0, stream>>>(x, rw, rb, T, tokE, tokW, counts);
  build_meta<<<1, 64, 0, stream>>>(counts, offsets, tilemeta);
  scatter_tokens<<<(A + 255) / 256, 256, 0, stream>>>(tokE, offsets, fill, rowsArr, apos, A);

  gemm_gate_up<<<dim3(MAXTILES, N_GU / BN), 256, 0, stream>>>(xb, guwb, gub, rowsArr, tilemeta, hact);
  gemm_down<<<dim3(MAXTILES, EMB / BN), 256, 0, stream>>>(hact, dwb, tilemeta, y);

  combine_out<<<(T * EMB / 4 + 255) / 256, 256, 0, stream>>>(y, db, tokE, tokW, apos, out, T);
}

// Round 2
// 199.528 us; speedup vs baseline: 1.5427x; 1.5427x over previous
//
#include <hip/hip_runtime.h>
#include <hip/hip_bf16.h>

#define EMB 1024
#define NEXP 8
#define NH 1024
#define N_GU 2048
#define TOPK 2

#define BM 128
#define BN 128
#define BK 32
#define MAXTILES 72

typedef __attribute__((ext_vector_type(4))) float f32x4;
typedef __attribute__((ext_vector_type(8))) short s16x8;
typedef __attribute__((ext_vector_type(4))) short s16x4;

typedef __attribute__((address_space(3))) unsigned int lds_u32;
typedef __attribute__((address_space(1))) const unsigned int glb_u32;

__device__ __forceinline__ void gl_lds16(const void* g, void* l) {
  __builtin_amdgcn_global_load_lds((glb_u32*)g, (lds_u32*)l, 16, 0, 0);
}

__device__ __forceinline__ unsigned short f2bf(float f) {
  union { float f; unsigned int u; } a; a.f = f;
  unsigned int u = a.u;
  unsigned int r = (u + 0x7FFFu + ((u >> 16) & 1u)) >> 16;
  return (unsigned short)r;
}

// ---------------- fp32 -> bf16 conversion ----------------
__global__ void convert_bf16(const float* __restrict__ in, unsigned short* __restrict__ out, int n4) {
  int i = blockIdx.x * blockDim.x + threadIdx.x;
  if (i >= n4) return;
  float4 v = ((const float4*)in)[i];
  s16x4 o;
  o[0] = (short)f2bf(v.x);
  o[1] = (short)f2bf(v.y);
  o[2] = (short)f2bf(v.z);
  o[3] = (short)f2bf(v.w);
  ((s16x4*)out)[i] = o;
}

// ---------------- router: scores, top-2, softmax (NO atomics) ----------------
__global__ void router_topk(const float* __restrict__ x, const float* __restrict__ rw,
                            const float* __restrict__ rb, int T,
                            int* __restrict__ tokE, float* __restrict__ tokW) {
  int gwid = (blockIdx.x * blockDim.x + threadIdx.x) >> 6;
  int lane = threadIdx.x & 63;
  if (gwid >= T) return;
  const float* h = x + (size_t)gwid * EMB;
  float hreg[16];
  #pragma unroll
  for (int i = 0; i < 16; ++i) hreg[i] = h[lane + 64 * i];
  float sc[NEXP];
  #pragma unroll
  for (int e = 0; e < NEXP; ++e) {
    const float* w = rw + e * EMB;
    float s = 0.f;
    #pragma unroll
    for (int i = 0; i < 16; ++i) s += hreg[i] * w[lane + 64 * i];
    #pragma unroll
    for (int off = 32; off > 0; off >>= 1) s += __shfl_xor(s, off);
    sc[e] = s + rb[e];
  }
  if (lane == 0) {
    int e0 = 0; float v0 = sc[0];
    #pragma unroll
    for (int e = 1; e < NEXP; ++e) if (sc[e] > v0) { v0 = sc[e]; e0 = e; }
    int e1 = -1; float v1 = -3.0e38f;
    #pragma unroll
    for (int e = 0; e < NEXP; ++e) { if (e == e0) continue; if (sc[e] > v1) { v1 = sc[e]; e1 = e; } }
    float ex = __expf(v1 - v0);
    float w0 = 1.f / (1.f + ex);
    float w1 = ex / (1.f + ex);
    tokE[gwid * 2] = e0; tokE[gwid * 2 + 1] = e1;
    tokW[gwid * 2] = w0; tokW[gwid * 2 + 1] = w1;
  }
}

// ---------------- histogram + offsets + tile map (single block, LDS atomics) ----------------
__global__ void count_meta(const int* __restrict__ tokE, int A,
                           int* __restrict__ offsets, int* __restrict__ tilemeta) {
  __shared__ int hist[NEXP];
  int t = threadIdx.x;
  if (t < NEXP) hist[t] = 0;
  __syncthreads();
  for (int i = t; i < A; i += blockDim.x) atomicAdd(&hist[tokE[i]], 1);
  __syncthreads();
  if (t == 0) {
    int off = 0, nt = 0;
    for (int e = 0; e < NEXP; ++e) {
      offsets[e] = off;
      int c = hist[e];
      int ntile = (c + BM - 1) / BM;
      for (int k = 0; k < ntile; ++k) {
        tilemeta[1 + nt * 3 + 0] = e;
        tilemeta[1 + nt * 3 + 1] = off + k * BM;
        tilemeta[1 + nt * 3 + 2] = off + c;
        nt++;
      }
      off += c;
    }
    offsets[NEXP] = off;
    tilemeta[0] = nt;
  }
}

// ---------------- scatter with wave-aggregated atomics ----------------
__global__ void scatter_tokens(const int* __restrict__ tokE, const int* __restrict__ offsets,
                               int* __restrict__ fill, int* __restrict__ rows,
                               int* __restrict__ apos, int A) {
  int i = blockIdx.x * blockDim.x + threadIdx.x;
  int lane = threadIdx.x & 63;
  int e = tokE[i];   // grid sized exactly: all threads active
  int p = -1;
  #pragma unroll
  for (int ex = 0; ex < NEXP; ++ex) {
    unsigned long long mask = __ballot(e == ex);
    if (mask) {
      int leader = __ffsll(mask) - 1;
      int cnt = __popcll(mask);
      int base = 0;
      if (lane == leader) base = atomicAdd(&fill[ex], cnt);
      base = __shfl(base, leader);
      if (e == ex) {
        int rank = __popcll(mask & ((1ull << lane) - 1ull));
        p = offsets[ex] + base + rank;
      }
    }
  }
  rows[p] = i >> 1;
  apos[i] = p;
}

// ---------------- grouped GEMM 1: gathered x rows @ gate_up_w[e]^T, fused SwiGLU ----------------
__global__ __launch_bounds__(256) void gemm_gate_up(
    const unsigned short* __restrict__ xb,
    const unsigned short* __restrict__ gub,
    const float* __restrict__ gu_bias,
    const int* __restrict__ rows,
    const int* __restrict__ tilemeta,
    unsigned short* __restrict__ hact) {
  __shared__ __align__(16) short As[BM * BK];
  __shared__ __align__(16) short Bs[BN * BK];
  int nt = tilemeta[0];
  int tileid = blockIdx.x;
  if (tileid >= nt) return;
  int e    = tilemeta[1 + tileid * 3 + 0];
  int m0   = tilemeta[1 + tileid * 3 + 1];
  int mEnd = tilemeta[1 + tileid * 3 + 2];
  int n0   = blockIdx.y * BN;

  int t = threadIdx.x;
  int lane = t & 63;
  int wid = t >> 6;
  int wr = wid >> 1, wc = wid & 1;

  // staging geometry: wave w instr q covers rows [q*64 + w*16, +16), lane l -> row +(l>>2), 16B col (l&3)
  int r0 = wid * 16 + (lane >> 2);
  int cB = (lane & 3) * 8;            // element offset
  int ai0 = m0 + r0;       if (ai0 >= mEnd) ai0 = mEnd - 1;
  int ai1 = m0 + 64 + r0;  if (ai1 >= mEnd) ai1 = mEnd - 1;
  const unsigned short* ga0 = xb + (size_t)rows[ai0] * EMB + cB;
  const unsigned short* ga1 = xb + (size_t)rows[ai1] * EMB + cB;
  const unsigned short* gb0 = gub + ((size_t)e * N_GU + n0 + r0) * EMB + cB;
  const unsigned short* gb1 = gub + ((size_t)e * N_GU + n0 + 64 + r0) * EMB + cB;
  short* la0 = As + wid * 512;               // wave-uniform dests
  short* la1 = As + 64 * BK + wid * 512;
  short* lb0 = Bs + wid * 512;
  short* lb1 = Bs + 64 * BK + wid * 512;

  int fr = lane & 15;
  int koff = (lane >> 4) * 8;

  f32x4 acc[4][4];
  #pragma unroll
  for (int i = 0; i < 4; ++i)
    #pragma unroll
    for (int j = 0; j < 4; ++j) acc[i][j] = (f32x4){0.f, 0.f, 0.f, 0.f};

  for (int k0 = 0; k0 < EMB; k0 += BK) {
    __syncthreads();
    gl_lds16(ga0 + k0, la0);
    gl_lds16(ga1 + k0, la1);
    gl_lds16(gb0 + k0, lb0);
    gl_lds16(gb1 + k0, lb1);
    __syncthreads();
    s16x8 a[4], b[4];
    #pragma unroll
    for (int i = 0; i < 4; ++i) a[i] = *(const s16x8*)(As + (wr * 64 + i * 16 + fr) * BK + koff);
    #pragma unroll
    for (int j = 0; j < 4; ++j) b[j] = *(const s16x8*)(Bs + (wc * 64 + j * 16 + fr) * BK + koff);
    #pragma unroll
    for (int i = 0; i < 4; ++i)
      #pragma unroll
      for (int j = 0; j < 4; ++j)
        acc[i][j] = __builtin_amdgcn_mfma_f32_16x16x32_bf16(a[i], b[j], acc[i][j], 0, 0, 0);
  }

  // epilogue: bias + SwiGLU (pair even/odd N columns via shfl_xor 1), write bf16 h_act
  const float* bias_e = gu_bias + (size_t)e * N_GU;
  int rbase = m0 + wr * 64 + ((lane >> 4) * 4);
  #pragma unroll
  for (int i = 0; i < 4; ++i) {
    #pragma unroll
    for (int j = 0; j < 4; ++j) {
      int n = n0 + wc * 64 + j * 16 + fr;
      float v[4], o[4];
      #pragma unroll
      for (int r = 0; r < 4; ++r) v[r] = acc[i][j][r] + bias_e[n];
      #pragma unroll
      for (int r = 0; r < 4; ++r) o[r] = __shfl_xor(v[r], 1);
      if ((lane & 1) == 0) {
        int outc = n >> 1;
        #pragma unroll
        for (int r = 0; r < 4; ++r) {
          int pos = rbase + i * 16 + r;
          if (pos < mEnd) {
            float g = v[r], u = o[r];
            float gc = fminf(fmaxf(g, -7.f), 7.f);
            float uc = fminf(fmaxf(u, -7.f), 7.f);
            float sig = 1.f / (1.f + __expf(-1.702f * g));
            float act = gc * sig * (uc + 1.f);
            hact[(size_t)pos * NH + outc] = f2bf(act);
          }
        }
      }
    }
  }
}

// ---------------- grouped GEMM 2: h_act @ down_w[e]^T ----------------
__global__ __launch_bounds__(256) void gemm_down(
    const unsigned short* __restrict__ hact,
    const unsigned short* __restrict__ dwb,
    const int* __restrict__ tilemeta,
    float* __restrict__ y) {
  __shared__ __align__(16) short As[BM * BK];
  __shared__ __align__(16) short Bs[BN * BK];
  int nt = tilemeta[0];
  int tileid = blockIdx.x;
  if (tileid >= nt) return;
  int e    = tilemeta[1 + tileid * 3 + 0];
  int m0   = tilemeta[1 + tileid * 3 + 1];
  int mEnd = tilemeta[1 + tileid * 3 + 2];
  int n0   = blockIdx.y * BN;

  int t = threadIdx.x;
  int lane = t & 63;
  int wid = t >> 6;
  int wr = wid >> 1, wc = wid & 1;

  int r0 = wid * 16 + (lane >> 2);
  int cB = (lane & 3) * 8;
  int ai0 = m0 + r0;       if (ai0 >= mEnd) ai0 = mEnd - 1;
  int ai1 = m0 + 64 + r0;  if (ai1 >= mEnd) ai1 = mEnd - 1;
  const unsigned short* ga0 = hact + (size_t)ai0 * NH + cB;
  const unsigned short* ga1 = hact + (size_t)ai1 * NH + cB;
  const unsigned short* gb0 = dwb + ((size_t)e * EMB + n0 + r0) * NH + cB;
  const unsigned short* gb1 = dwb + ((size_t)e * EMB + n0 + 64 + r0) * NH + cB;
  short* la0 = As + wid * 512;
  short* la1 = As + 64 * BK + wid * 512;
  short* lb0 = Bs + wid * 512;
  short* lb1 = Bs + 64 * BK + wid * 512;

  int fr = lane & 15;
  int koff = (lane >> 4) * 8;

  f32x4 acc[4][4];
  #pragma unroll
  for (int i = 0; i < 4; ++i)
    #pragma unroll
    for (int j = 0; j < 4; ++j) acc[i][j] = (f32x4){0.f, 0.f, 0.f, 0.f};

  for (int k0 = 0; k0 < NH; k0 += BK) {
    __syncthreads();
    gl_lds16(ga0 + k0, la0);
    gl_lds16(ga1 + k0, la1);
    gl_lds16(gb0 + k0, lb0);
    gl_lds16(gb1 + k0, lb1);
    __syncthreads();
    s16x8 a[4], b[4];
    #pragma unroll
    for (int i = 0; i < 4; ++i) a[i] = *(const s16x8*)(As + (wr * 64 + i * 16 + fr) * BK + koff);
    #pragma unroll
    for (int j = 0; j < 4; ++j) b[j] = *(const s16x8*)(Bs + (wc * 64 + j * 16 + fr) * BK + koff);
    #pragma unroll
    for (int i = 0; i < 4; ++i)
      #pragma unroll
      for (int j = 0; j < 4; ++j)
        acc[i][j] = __builtin_amdgcn_mfma_f32_16x16x32_bf16(a[i], b[j], acc[i][j], 0, 0, 0);
  }

  int rbase = m0 + wr * 64 + ((lane >> 4) * 4);
  #pragma unroll
  for (int i = 0; i < 4; ++i) {
    #pragma unroll
    for (int j = 0; j < 4; ++j) {
      int n = n0 + wc * 64 + j * 16 + fr;
      #pragma unroll
      for (int r = 0; r < 4; ++r) {
        int pos = rbase + i * 16 + r;
        if (pos < mEnd) y[(size_t)pos * EMB + n] = acc[i][j][r];
      }
    }
  }
}

// ---------------- final combine ----------------
__global__ void combine_out(const float* __restrict__ y, const float* __restrict__ down_b,
                            const int* __restrict__ tokE, const float* __restrict__ tokW,
                            const int* __restrict__ apos, float* __restrict__ out, int T) {
  int i = blockIdx.x * blockDim.x + threadIdx.x;
  int tot = T * (EMB / 4);
  if (i >= tot) return;
  int tok = i >> 8;
  int c = i & 255;
  int e0 = tokE[tok * 2], e1 = tokE[tok * 2 + 1];
  float w0 = tokW[tok * 2], w1 = tokW[tok * 2 + 1];
  int p0 = apos[tok * 2], p1 = apos[tok * 2 + 1];
  float4 y0 = ((const float4*)(y + (size_t)p0 * EMB))[c];
  float4 y1 = ((const float4*)(y + (size_t)p1 * EMB))[c];
  float4 b0 = ((const float4*)(down_b + (size_t)e0 * EMB))[c];
  float4 b1 = ((const float4*)(down_b + (size_t)e1 * EMB))[c];
  float4 o;
  o.x = w0 * (y0.x + b0.x) + w1 * (y1.x + b1.x);
  o.y = w0 * (y0.y + b0.y) + w1 * (y1.y + b1.y);
  o.z = w0 * (y0.z + b0.z) + w1 * (y1.z + b1.z);
  o.w = w0 * (y0.w + b0.w) + w1 * (y1.w + b1.w);
  ((float4*)out)[i] = o;
}

extern "C" void kernel_launch(void* const* d_in, const int* in_sizes, int n_in,
                              void* d_out, int out_size, void* d_ws, size_t ws_size,
                              hipStream_t stream) {
  const float* x   = (const float*)d_in[0];
  const float* rw  = (const float*)d_in[1];
  const float* rb  = (const float*)d_in[2];
  const float* guw = (const float*)d_in[3];
  const float* gub = (const float*)d_in[4];
  const float* dw  = (const float*)d_in[5];
  const float* db  = (const float*)d_in[6];
  float* out = (float*)d_out;

  int T = in_sizes[0] / EMB;   // 4096
  int A = T * TOPK;            // 8192

  char* ws = (char*)d_ws;
  size_t off = 0;
  auto alloc = [&](size_t bytes) -> void* {
    void* p = ws + off;
    off = (off + bytes + 255) & ~((size_t)255);
    return p;
  };
  unsigned short* xb   = (unsigned short*)alloc((size_t)T * EMB * 2);
  unsigned short* guwb = (unsigned short*)alloc((size_t)NEXP * N_GU * EMB * 2);
  unsigned short* dwb  = (unsigned short*)alloc((size_t)NEXP * EMB * NH * 2);
  unsigned short* hact = (unsigned short*)alloc((size_t)A * NH * 2);
  float* y             = (float*)alloc((size_t)A * EMB * 4);
  int*   tokE    = (int*)alloc((size_t)A * 4);
  float* tokW    = (float*)alloc((size_t)A * 4);
  int*   apos    = (int*)alloc((size_t)A * 4);
  int*   rowsArr = (int*)alloc((size_t)A * 4);
  int*   fill    = (int*)alloc(NEXP * 4);
  int*   offsets = (int*)alloc((NEXP + 1) * 4);
  int*   tilemeta= (int*)alloc((1 + MAXTILES * 3) * 4);

  hipMemsetAsync(fill, 0, NEXP * 4, stream);

  int thr = 256;
  int n4x = T * EMB / 4;
  int n4g = NEXP * N_GU * EMB / 4;
  int n4d = NEXP * EMB * NH / 4;
  convert_bf16<<<(n4x + thr - 1) / thr, thr, 0, stream>>>(x, xb, n4x);
  convert_bf16<<<(n4g + thr - 1) / thr, thr, 0, stream>>>(guw, guwb, n4g);
  convert_bf16<<<(n4d + thr - 1) / thr, thr, 0, stream>>>(dw, dwb, n4d);

  router_topk<<<T / 4, 256, 0, stream>>>(x, rw, rb, T, tokE, tokW);
  count_meta<<<1, 1024, 0, stream>>>(tokE, A, offsets, tilemeta);
  scatter_tokens<<<A / 256, 256, 0, stream>>>(tokE, offsets, fill, rowsArr, apos, A);

  gemm_gate_up<<<dim3(MAXTILES, N_GU / BN), 256, 0, stream>>>(xb, guwb, gub, rowsArr, tilemeta, hact);
  gemm_down<<<dim3(MAXTILES, EMB / BN), 256, 0, stream>>>(hact, dwb, tilemeta, y);

  combine_out<<<(T * EMB / 4 + 255) / 256, 256, 0, stream>>>(y, db, tokE, tokW, apos, out, T);
}

// Round 3
// 194.148 us; speedup vs baseline: 1.5854x; 1.0277x over previous
//
#include <hip/hip_runtime.h>
#include <hip/hip_bf16.h>

#define EMB 1024
#define NEXP 8
#define NH 1024
#define N_GU 2048
#define TOPK 2

#define BM 128
#define BN 128
#define BK 64
#define KTILES 16      // 1024 / 64
#define MAXTILES 72

typedef __attribute__((ext_vector_type(4))) float f32x4;
typedef __attribute__((ext_vector_type(8))) short s16x8;
typedef __attribute__((ext_vector_type(4))) short s16x4;

typedef __attribute__((address_space(3))) unsigned int lds_u32;
typedef __attribute__((address_space(1))) const unsigned int glb_u32;

__device__ __forceinline__ void gl_lds16(const void* g, void* l) {
  __builtin_amdgcn_global_load_lds((glb_u32*)g, (lds_u32*)l, 16, 0, 0);
}

__device__ __forceinline__ unsigned short f2bf(float f) {
  union { float f; unsigned int u; } a; a.f = f;
  unsigned int u = a.u;
  unsigned int r = (u + 0x7FFFu + ((u >> 16) & 1u)) >> 16;
  return (unsigned short)r;
}

// bijective chunked XCD swizzle (m204): nwg must be the real grid size
__device__ __forceinline__ int xcd_swz(int bid, int nwg) {
  int q = nwg >> 3, r = nwg & 7;
  int xcd = bid & 7, pos = bid >> 3;
  int base = (xcd < r) ? xcd * (q + 1) : r * (q + 1) + (xcd - r) * q;
  return base + pos;
}

// ---------------- fp32 -> bf16 conversion ----------------
__global__ void convert_bf16(const float* __restrict__ in, unsigned short* __restrict__ out, int n4) {
  int i = blockIdx.x * blockDim.x + threadIdx.x;
  if (i >= n4) return;
  float4 v = ((const float4*)in)[i];
  s16x4 o;
  o[0] = (short)f2bf(v.x);
  o[1] = (short)f2bf(v.y);
  o[2] = (short)f2bf(v.z);
  o[3] = (short)f2bf(v.w);
  ((s16x4*)out)[i] = o;
}

// ---------------- router ----------------
__global__ void router_topk(const float* __restrict__ x, const float* __restrict__ rw,
                            const float* __restrict__ rb, int T,
                            int* __restrict__ tokE, float* __restrict__ tokW) {
  int gwid = (blockIdx.x * blockDim.x + threadIdx.x) >> 6;
  int lane = threadIdx.x & 63;
  if (gwid >= T) return;
  const float* h = x + (size_t)gwid * EMB;
  float hreg[16];
  #pragma unroll
  for (int i = 0; i < 16; ++i) hreg[i] = h[lane + 64 * i];
  float sc[NEXP];
  #pragma unroll
  for (int e = 0; e < NEXP; ++e) {
    const float* w = rw + e * EMB;
    float s = 0.f;
    #pragma unroll
    for (int i = 0; i < 16; ++i) s += hreg[i] * w[lane + 64 * i];
    #pragma unroll
    for (int off = 32; off > 0; off >>= 1) s += __shfl_xor(s, off);
    sc[e] = s + rb[e];
  }
  if (lane == 0) {
    int e0 = 0; float v0 = sc[0];
    #pragma unroll
    for (int e = 1; e < NEXP; ++e) if (sc[e] > v0) { v0 = sc[e]; e0 = e; }
    int e1 = -1; float v1 = -3.0e38f;
    #pragma unroll
    for (int e = 0; e < NEXP; ++e) { if (e == e0) continue; if (sc[e] > v1) { v1 = sc[e]; e1 = e; } }
    float ex = __expf(v1 - v0);
    float w0 = 1.f / (1.f + ex);
    float w1 = ex / (1.f + ex);
    tokE[gwid * 2] = e0; tokE[gwid * 2 + 1] = e1;
    tokW[gwid * 2] = w0; tokW[gwid * 2 + 1] = w1;
  }
}

// ---------------- histogram + offsets + tile map ----------------
__global__ void count_meta(const int* __restrict__ tokE, int A,
                           int* __restrict__ offsets, int* __restrict__ tilemeta) {
  __shared__ int hist[NEXP];
  int t = threadIdx.x;
  if (t < NEXP) hist[t] = 0;
  __syncthreads();
  for (int i = t; i < A; i += blockDim.x) atomicAdd(&hist[tokE[i]], 1);
  __syncthreads();
  if (t == 0) {
    int off = 0, nt = 0;
    for (int e = 0; e < NEXP; ++e) {
      offsets[e] = off;
      int c = hist[e];
      int ntile = (c + BM - 1) / BM;
      for (int k = 0; k < ntile; ++k) {
        tilemeta[1 + nt * 3 + 0] = e;
        tilemeta[1 + nt * 3 + 1] = off + k * BM;
        tilemeta[1 + nt * 3 + 2] = off + c;
        nt++;
      }
      off += c;
    }
    offsets[NEXP] = off;
    tilemeta[0] = nt;
  }
}

// ---------------- scatter with wave-aggregated atomics ----------------
__global__ void scatter_tokens(const int* __restrict__ tokE, const int* __restrict__ offsets,
                               int* __restrict__ fill, int* __restrict__ rows,
                               int* __restrict__ apos, int A) {
  int i = blockIdx.x * blockDim.x + threadIdx.x;
  int lane = threadIdx.x & 63;
  int e = tokE[i];
  int p = -1;
  #pragma unroll
  for (int ex = 0; ex < NEXP; ++ex) {
    unsigned long long mask = __ballot(e == ex);
    if (mask) {
      int leader = __ffsll(mask) - 1;
      int cnt = __popcll(mask);
      int base = 0;
      if (lane == leader) base = atomicAdd(&fill[ex], cnt);
      base = __shfl(base, leader);
      if (e == ex) {
        int rank = __popcll(mask & ((1ull << lane) - 1ull));
        p = offsets[ex] + base + rank;
      }
    }
  }
  rows[p] = i >> 1;
  apos[i] = p;
}

// ---------------- grouped GEMM 1: gathered x @ gate_up_w[e]^T, fused SwiGLU ----------------
// grid: 1D, nwg = MAXTILES*16; decode y fast (A-tile reuse adjacency) + XCD swizzle
__global__ __launch_bounds__(256) void gemm_gate_up(
    const unsigned short* __restrict__ xb,
    const unsigned short* __restrict__ gub,
    const float* __restrict__ gu_bias,
    const int* __restrict__ rows,
    const int* __restrict__ tilemeta,
    unsigned short* __restrict__ hact) {
  __shared__ __align__(16) short As[2][BM * BK];
  __shared__ __align__(16) short Bs[2][BN * BK];
  int wg = xcd_swz(blockIdx.x, gridDim.x);
  int tileid = wg >> 4;          // y = wg & 15 fast axis
  int n0 = (wg & 15) * BN;
  int nt = tilemeta[0];
  if (tileid >= nt) return;
  int e    = tilemeta[1 + tileid * 3 + 0];
  int m0   = tilemeta[1 + tileid * 3 + 1];
  int mEnd = tilemeta[1 + tileid * 3 + 2];

  int t = threadIdx.x;
  int lane = t & 63;
  int wid = t >> 6;
  int wr = wid >> 1, wc = wid & 1;

  // staging: wave wid, instr q -> 8 rows starting at wid*32+q*8; lane covers row +(l>>3),
  // 16B chunk (l&7) with pre-swizzled source col (st_16x32: flip 32B half when l>=32)
  int srow = lane >> 3;
  int scol = ((lane & 7) * 8) ^ ((lane >> 5) << 4);   // element offset, pre-swizzled
  const unsigned short* ga[4];
  const unsigned short* gb[4];
  int dstoff[4];
  #pragma unroll
  for (int q = 0; q < 4; ++q) {
    int rt = wid * 32 + q * 8 + srow;                  // tile row 0..127
    int ai = m0 + rt; if (ai >= mEnd) ai = mEnd - 1;
    ga[q] = xb + (size_t)rows[ai] * EMB + scol;
    gb[q] = gub + ((size_t)e * N_GU + n0 + rt) * EMB + scol;
    dstoff[q] = (wid * 32 + q * 8) * BK;               // wave-uniform
  }

  int fr = lane & 15;
  int q8 = (lane >> 4) * 8;
  int sx = ((fr >> 2) & 1) << 4;                       // read-side swizzle (elem)

  f32x4 acc[4][4];
  #pragma unroll
  for (int i = 0; i < 4; ++i)
    #pragma unroll
    for (int j = 0; j < 4; ++j) acc[i][j] = (f32x4){0.f, 0.f, 0.f, 0.f};

  // prologue: stage tile 0 into buf 0
  #pragma unroll
  for (int q = 0; q < 4; ++q) {
    gl_lds16(ga[q], &As[0][dstoff[q]]);
    gl_lds16(gb[q], &Bs[0][dstoff[q]]);
  }

  int cur = 0;
  for (int tk = 0; tk < KTILES; ++tk) {
    __syncthreads();   // implicit vmcnt(0)+lgkmcnt(0): STAGE(tk) landed for ALL waves
    if (tk + 1 < KTILES) {
      int k0 = (tk + 1) * BK;
      #pragma unroll
      for (int q = 0; q < 4; ++q) {
        gl_lds16(ga[q] + k0, &As[cur ^ 1][dstoff[q]]);
        gl_lds16(gb[q] + k0, &Bs[cur ^ 1][dstoff[q]]);
      }
    }
    #pragma unroll
    for (int kk = 0; kk < BK; kk += 32) {
      s16x8 a[4], b[4];
      #pragma unroll
      for (int i = 0; i < 4; ++i)
        a[i] = *(const s16x8*)(&As[cur][(((wr * 64 + i * 16 + fr) * BK + kk + q8) ^ sx)]);
      #pragma unroll
      for (int j = 0; j < 4; ++j)
        b[j] = *(const s16x8*)(&Bs[cur][(((wc * 64 + j * 16 + fr) * BK + kk + q8) ^ sx)]);
      #pragma unroll
      for (int i = 0; i < 4; ++i)
        #pragma unroll
        for (int j = 0; j < 4; ++j)
          acc[i][j] = __builtin_amdgcn_mfma_f32_16x16x32_bf16(a[i], b[j], acc[i][j], 0, 0, 0);
    }
    cur ^= 1;
  }

  // epilogue: bias + SwiGLU (pair even/odd N via shfl_xor 1) -> bf16 hact
  const float* bias_e = gu_bias + (size_t)e * N_GU;
  int rbase = m0 + wr * 64 + ((lane >> 4) * 4);
  #pragma unroll
  for (int i = 0; i < 4; ++i) {
    #pragma unroll
    for (int j = 0; j < 4; ++j) {
      int n = n0 + wc * 64 + j * 16 + fr;
      float v[4], o[4];
      #pragma unroll
      for (int r = 0; r < 4; ++r) v[r] = acc[i][j][r] + bias_e[n];
      #pragma unroll
      for (int r = 0; r < 4; ++r) o[r] = __shfl_xor(v[r], 1);
      if ((lane & 1) == 0) {
        int outc = n >> 1;
        #pragma unroll
        for (int r = 0; r < 4; ++r) {
          int pos = rbase + i * 16 + r;
          if (pos < mEnd) {
            float g = v[r], u = o[r];
            float gc = fminf(fmaxf(g, -7.f), 7.f);
            float uc = fminf(fmaxf(u, -7.f), 7.f);
            float sig = 1.f / (1.f + __expf(-1.702f * g));
            float act = gc * sig * (uc + 1.f);
            hact[(size_t)pos * NH + outc] = f2bf(act);
          }
        }
      }
    }
  }
}

// ---------------- grouped GEMM 2: hact @ down_w[e]^T ----------------
__global__ __launch_bounds__(256) void gemm_down(
    const unsigned short* __restrict__ hact,
    const unsigned short* __restrict__ dwb,
    const int* __restrict__ tilemeta,
    float* __restrict__ y) {
  __shared__ __align__(16) short As[2][BM * BK];
  __shared__ __align__(16) short Bs[2][BN * BK];
  int wg = xcd_swz(blockIdx.x, gridDim.x);
  int tileid = wg >> 3;          // y = wg & 7 fast axis (EMB/BN = 8)
  int n0 = (wg & 7) * BN;
  int nt = tilemeta[0];
  if (tileid >= nt) return;
  int e    = tilemeta[1 + tileid * 3 + 0];
  int m0   = tilemeta[1 + tileid * 3 + 1];
  int mEnd = tilemeta[1 + tileid * 3 + 2];

  int t = threadIdx.x;
  int lane = t & 63;
  int wid = t >> 6;
  int wr = wid >> 1, wc = wid & 1;

  int srow = lane >> 3;
  int scol = ((lane & 7) * 8) ^ ((lane >> 5) << 4);
  const unsigned short* ga[4];
  const unsigned short* gb[4];
  int dstoff[4];
  #pragma unroll
  for (int q = 0; q < 4; ++q) {
    int rt = wid * 32 + q * 8 + srow;
    int ai = m0 + rt; if (ai >= mEnd) ai = mEnd - 1;
    ga[q] = hact + (size_t)ai * NH + scol;
    gb[q] = dwb + ((size_t)e * EMB + n0 + rt) * NH + scol;
    dstoff[q] = (wid * 32 + q * 8) * BK;
  }

  int fr = lane & 15;
  int q8 = (lane >> 4) * 8;
  int sx = ((fr >> 2) & 1) << 4;

  f32x4 acc[4][4];
  #pragma unroll
  for (int i = 0; i < 4; ++i)
    #pragma unroll
    for (int j = 0; j < 4; ++j) acc[i][j] = (f32x4){0.f, 0.f, 0.f, 0.f};

  #pragma unroll
  for (int q = 0; q < 4; ++q) {
    gl_lds16(ga[q], &As[0][dstoff[q]]);
    gl_lds16(gb[q], &Bs[0][dstoff[q]]);
  }

  int cur = 0;
  for (int tk = 0; tk < KTILES; ++tk) {
    __syncthreads();
    if (tk + 1 < KTILES) {
      int k0 = (tk + 1) * BK;
      #pragma unroll
      for (int q = 0; q < 4; ++q) {
        gl_lds16(ga[q] + k0, &As[cur ^ 1][dstoff[q]]);
        gl_lds16(gb[q] + k0, &Bs[cur ^ 1][dstoff[q]]);
      }
    }
    #pragma unroll
    for (int kk = 0; kk < BK; kk += 32) {
      s16x8 a[4], b[4];
      #pragma unroll
      for (int i = 0; i < 4; ++i)
        a[i] = *(const s16x8*)(&As[cur][(((wr * 64 + i * 16 + fr) * BK + kk + q8) ^ sx)]);
      #pragma unroll
      for (int j = 0; j < 4; ++j)
        b[j] = *(const s16x8*)(&Bs[cur][(((wc * 64 + j * 16 + fr) * BK + kk + q8) ^ sx)]);
      #pragma unroll
      for (int i = 0; i < 4; ++i)
        #pragma unroll
        for (int j = 0; j < 4; ++j)
          acc[i][j] = __builtin_amdgcn_mfma_f32_16x16x32_bf16(a[i], b[j], acc[i][j], 0, 0, 0);
    }
    cur ^= 1;
  }

  int rbase = m0 + wr * 64 + ((lane >> 4) * 4);
  #pragma unroll
  for (int i = 0; i < 4; ++i) {
    #pragma unroll
    for (int j = 0; j < 4; ++j) {
      int n = n0 + wc * 64 + j * 16 + fr;
      #pragma unroll
      for (int r = 0; r < 4; ++r) {
        int pos = rbase + i * 16 + r;
        if (pos < mEnd) y[(size_t)pos * EMB + n] = acc[i][j][r];
      }
    }
  }
}

// ---------------- final combine ----------------
__global__ void combine_out(const float* __restrict__ y, const float* __restrict__ down_b,
                            const int* __restrict__ tokE, const float* __restrict__ tokW,
                            const int* __restrict__ apos, float* __restrict__ out, int T) {
  int i = blockIdx.x * blockDim.x + threadIdx.x;
  int tot = T * (EMB / 4);
  if (i >= tot) return;
  int tok = i >> 8;
  int c = i & 255;
  int e0 = tokE[tok * 2], e1 = tokE[tok * 2 + 1];
  float w0 = tokW[tok * 2], w1 = tokW[tok * 2 + 1];
  int p0 = apos[tok * 2], p1 = apos[tok * 2 + 1];
  float4 y0 = ((const float4*)(y + (size_t)p0 * EMB))[c];
  float4 y1 = ((const float4*)(y + (size_t)p1 * EMB))[c];
  float4 b0 = ((const float4*)(down_b + (size_t)e0 * EMB))[c];
  float4 b1 = ((const float4*)(down_b + (size_t)e1 * EMB))[c];
  float4 o;
  o.x = w0 * (y0.x + b0.x) + w1 * (y1.x + b1.x);
  o.y = w0 * (y0.y + b0.y) + w1 * (y1.y + b1.y);
  o.z = w0 * (y0.z + b0.z) + w1 * (y1.z + b1.z);
  o.w = w0 * (y0.w + b0.w) + w1 * (y1.w + b1.w);
  ((float4*)out)[i] = o;
}

extern "C" void kernel_launch(void* const* d_in, const int* in_sizes, int n_in,
                              void* d_out, int out_size, void* d_ws, size_t ws_size,
                              hipStream_t stream) {
  const float* x   = (const float*)d_in[0];
  const float* rw  = (const float*)d_in[1];
  const float* rb  = (const float*)d_in[2];
  const float* guw = (const float*)d_in[3];
  const float* gub = (const float*)d_in[4];
  const float* dw  = (const float*)d_in[5];
  const float* db  = (const float*)d_in[6];
  float* out = (float*)d_out;

  int T = in_sizes[0] / EMB;   // 4096
  int A = T * TOPK;            // 8192

  char* ws = (char*)d_ws;
  size_t off = 0;
  auto alloc = [&](size_t bytes) -> void* {
    void* p = ws + off;
    off = (off + bytes + 255) & ~((size_t)255);
    return p;
  };
  unsigned short* xb   = (unsigned short*)alloc((size_t)T * EMB * 2);
  unsigned short* guwb = (unsigned short*)alloc((size_t)NEXP * N_GU * EMB * 2);
  unsigned short* dwb  = (unsigned short*)alloc((size_t)NEXP * EMB * NH * 2);
  unsigned short* hact = (unsigned short*)alloc((size_t)A * NH * 2);
  float* y             = (float*)alloc((size_t)A * EMB * 4);
  int*   tokE    = (int*)alloc((size_t)A * 4);
  float* tokW    = (float*)alloc((size_t)A * 4);
  int*   apos    = (int*)alloc((size_t)A * 4);
  int*   rowsArr = (int*)alloc((size_t)A * 4);
  int*   fill    = (int*)alloc(NEXP * 4);
  int*   offsets = (int*)alloc((NEXP + 1) * 4);
  int*   tilemeta= (int*)alloc((1 + MAXTILES * 3) * 4);

  hipMemsetAsync(fill, 0, NEXP * 4, stream);

  int thr = 256;
  int n4x = T * EMB / 4;
  int n4g = NEXP * N_GU * EMB / 4;
  int n4d = NEXP * EMB * NH / 4;
  convert_bf16<<<(n4x + thr - 1) / thr, thr, 0, stream>>>(x, xb, n4x);
  convert_bf16<<<(n4g + thr - 1) / thr, thr, 0, stream>>>(guw, guwb, n4g);
  convert_bf16<<<(n4d + thr - 1) / thr, thr, 0, stream>>>(dw, dwb, n4d);

  router_topk<<<T / 4, 256, 0, stream>>>(x, rw, rb, T, tokE, tokW);
  count_meta<<<1, 1024, 0, stream>>>(tokE, A, offsets, tilemeta);
  scatter_tokens<<<A / 256, 256, 0, stream>>>(tokE, offsets, fill, rowsArr, apos, A);

  gemm_gate_up<<<MAXTILES * (N_GU / BN), 256, 0, stream>>>(xb, guwb, gub, rowsArr, tilemeta, hact);
  gemm_down<<<MAXTILES * (EMB / BN), 256, 0, stream>>>(hact, dwb, tilemeta, y);

  combine_out<<<(T * EMB / 4 + 255) / 256, 256, 0, stream>>>(y, db, tokE, tokW, apos, out, T);
}

// Round 4
// 191.532 us; speedup vs baseline: 1.6071x; 1.0137x over previous
//
#include <hip/hip_runtime.h>
#include <hip/hip_bf16.h>

#define EMB 1024
#define NEXP 8
#define NH 1024
#define N_GU 2048
#define TOPK 2

#define BM 128
#define BN 128
#define BK 64
#define KTILES 16      // 1024 / 64
#define MAXTILES 72

typedef __attribute__((ext_vector_type(4))) float f32x4;
typedef __attribute__((ext_vector_type(8))) short s16x8;
typedef __attribute__((ext_vector_type(4))) short s16x4;

typedef __attribute__((address_space(3))) unsigned int lds_u32;
typedef __attribute__((address_space(1))) const unsigned int glb_u32;

__device__ __forceinline__ void gl_lds16(const void* g, void* l) {
  __builtin_amdgcn_global_load_lds((glb_u32*)g, (lds_u32*)l, 16, 0, 0);
}

__device__ __forceinline__ unsigned short f2bf(float f) {
  union { float f; unsigned int u; } a; a.f = f;
  unsigned int u = a.u;
  unsigned int r = (u + 0x7FFFu + ((u >> 16) & 1u)) >> 16;
  return (unsigned short)r;
}

// bijective chunked XCD swizzle (m204)
__device__ __forceinline__ int xcd_swz(int bid, int nwg) {
  int q = nwg >> 3, r = nwg & 7;
  int xcd = bid & 7, pos = bid >> 3;
  int base = (xcd < r) ? xcd * (q + 1) : r * (q + 1) + (xcd - r) * q;
  return base + pos;
}

// ---------------- fused fp32 -> bf16 conversion (3 segments, grid-stride) ----------------
__global__ void convert_all(const float* __restrict__ a, unsigned short* __restrict__ oa, int n4a,
                            const float* __restrict__ b, unsigned short* __restrict__ ob, int n4b,
                            const float* __restrict__ c, unsigned short* __restrict__ oc, int n4c) {
  int tot = n4a + n4b + n4c;
  for (int i = blockIdx.x * blockDim.x + threadIdx.x; i < tot; i += gridDim.x * blockDim.x) {
    const float* src; unsigned short* dst; int k;
    if (i < n4a) { src = a; dst = oa; k = i; }
    else if (i < n4a + n4b) { src = b; dst = ob; k = i - n4a; }
    else { src = c; dst = oc; k = i - n4a - n4b; }
    float4 v = ((const float4*)src)[k];
    s16x4 o;
    o[0] = (short)f2bf(v.x);
    o[1] = (short)f2bf(v.y);
    o[2] = (short)f2bf(v.z);
    o[3] = (short)f2bf(v.w);
    ((s16x4*)dst)[k] = o;
  }
}

// ---------------- router ----------------
__global__ void router_topk(const float* __restrict__ x, const float* __restrict__ rw,
                            const float* __restrict__ rb, int T,
                            int* __restrict__ tokE, float* __restrict__ tokW) {
  int gwid = (blockIdx.x * blockDim.x + threadIdx.x) >> 6;
  int lane = threadIdx.x & 63;
  if (gwid >= T) return;
  const float* h = x + (size_t)gwid * EMB;
  float hreg[16];
  #pragma unroll
  for (int i = 0; i < 16; ++i) hreg[i] = h[lane + 64 * i];
  float sc[NEXP];
  #pragma unroll
  for (int e = 0; e < NEXP; ++e) {
    const float* w = rw + e * EMB;
    float s = 0.f;
    #pragma unroll
    for (int i = 0; i < 16; ++i) s += hreg[i] * w[lane + 64 * i];
    #pragma unroll
    for (int off = 32; off > 0; off >>= 1) s += __shfl_xor(s, off);
    sc[e] = s + rb[e];
  }
  if (lane == 0) {
    int e0 = 0; float v0 = sc[0];
    #pragma unroll
    for (int e = 1; e < NEXP; ++e) if (sc[e] > v0) { v0 = sc[e]; e0 = e; }
    int e1 = -1; float v1 = -3.0e38f;
    #pragma unroll
    for (int e = 0; e < NEXP; ++e) { if (e == e0) continue; if (sc[e] > v1) { v1 = sc[e]; e1 = e; } }
    float ex = __expf(v1 - v0);
    float w0 = 1.f / (1.f + ex);
    float w1 = ex / (1.f + ex);
    tokE[gwid * 2] = e0; tokE[gwid * 2 + 1] = e1;
    tokW[gwid * 2] = w0; tokW[gwid * 2 + 1] = w1;
  }
}

// ---------------- histogram + offsets + tile map ----------------
__global__ void count_meta(const int* __restrict__ tokE, int A,
                           int* __restrict__ offsets, int* __restrict__ tilemeta) {
  __shared__ int hist[NEXP];
  int t = threadIdx.x;
  if (t < NEXP) hist[t] = 0;
  __syncthreads();
  for (int i = t; i < A; i += blockDim.x) atomicAdd(&hist[tokE[i]], 1);
  __syncthreads();
  if (t == 0) {
    int off = 0, nt = 0;
    for (int e = 0; e < NEXP; ++e) {
      offsets[e] = off;
      int c = hist[e];
      int ntile = (c + BM - 1) / BM;
      for (int k = 0; k < ntile; ++k) {
        tilemeta[1 + nt * 3 + 0] = e;
        tilemeta[1 + nt * 3 + 1] = off + k * BM;
        tilemeta[1 + nt * 3 + 2] = off + c;
        nt++;
      }
      off += c;
    }
    offsets[NEXP] = off;
    tilemeta[0] = nt;
  }
}

// ---------------- scatter with wave-aggregated atomics ----------------
__global__ void scatter_tokens(const int* __restrict__ tokE, const int* __restrict__ offsets,
                               int* __restrict__ fill, int* __restrict__ rows,
                               int* __restrict__ apos, int A) {
  int i = blockIdx.x * blockDim.x + threadIdx.x;
  int lane = threadIdx.x & 63;
  int e = tokE[i];
  int p = -1;
  #pragma unroll
  for (int ex = 0; ex < NEXP; ++ex) {
    unsigned long long mask = __ballot(e == ex);
    if (mask) {
      int leader = __ffsll(mask) - 1;
      int cnt = __popcll(mask);
      int base = 0;
      if (lane == leader) base = atomicAdd(&fill[ex], cnt);
      base = __shfl(base, leader);
      if (e == ex) {
        int rank = __popcll(mask & ((1ull << lane) - 1ull));
        p = offsets[ex] + base + rank;
      }
    }
  }
  rows[p] = i >> 1;
  apos[i] = p;
}

// ---------------- grouped GEMM 1: gathered x @ gate_up_w[e]^T, fused SwiGLU ----------------
__global__ __launch_bounds__(256) void gemm_gate_up(
    const unsigned short* __restrict__ xb,
    const unsigned short* __restrict__ gub,
    const float* __restrict__ gu_bias,
    const int* __restrict__ rows,
    const int* __restrict__ tilemeta,
    unsigned short* __restrict__ hact) {
  __shared__ __align__(16) short As[2][BM * BK];
  __shared__ __align__(16) short Bs[2][BN * BK];
  int wg = xcd_swz(blockIdx.x, gridDim.x);
  int tileid = wg >> 4;          // y = wg & 15 fast axis
  int n0 = (wg & 15) * BN;
  int nt = tilemeta[0];
  if (tileid >= nt) return;
  int e    = tilemeta[1 + tileid * 3 + 0];
  int m0   = tilemeta[1 + tileid * 3 + 1];
  int mEnd = tilemeta[1 + tileid * 3 + 2];

  int t = threadIdx.x;
  int lane = t & 63;
  int wid = t >> 6;
  int wr = wid >> 1, wc = wid & 1;

  // staging: instr q covers rows wid*32+q*8 .. +8; lane l -> row +(l>>3), LDS chunk (l&7).
  // SOURCE pre-swizzle (rule #21): fetch global chunk (l&7) ^ (row&7), row&7 = (l>>3)&7.
  int srow = lane >> 3;
  int scol = (((lane & 7) ^ (srow & 7)) * 8);     // element offset in row, pre-swizzled
  const unsigned short* ga[4];
  const unsigned short* gb[4];
  int dstoff[4];
  #pragma unroll
  for (int q = 0; q < 4; ++q) {
    int rt = wid * 32 + q * 8 + srow;
    int ai = m0 + rt; if (ai >= mEnd) ai = mEnd - 1;
    ga[q] = xb + (size_t)rows[ai] * EMB + scol;
    gb[q] = gub + ((size_t)e * N_GU + n0 + rt) * EMB + scol;
    dstoff[q] = (wid * 32 + q * 8) * BK;           // wave-uniform
  }

  int fr = lane & 15;
  int q8 = (lane >> 4) * 8;
  int rsw = (fr & 7) << 3;                         // read-side swizzle (elem), row&7 = fr&7

  f32x4 acc[4][4];
  #pragma unroll
  for (int i = 0; i < 4; ++i)
    #pragma unroll
    for (int j = 0; j < 4; ++j) acc[i][j] = (f32x4){0.f, 0.f, 0.f, 0.f};

  #pragma unroll
  for (int q = 0; q < 4; ++q) {
    gl_lds16(ga[q], &As[0][dstoff[q]]);
    gl_lds16(gb[q], &Bs[0][dstoff[q]]);
  }

  int cur = 0;
  for (int tk = 0; tk < KTILES; ++tk) {
    __syncthreads();   // drains STAGE(tk) for all waves
    if (tk + 1 < KTILES) {
      int k0 = (tk + 1) * BK;
      #pragma unroll
      for (int q = 0; q < 4; ++q) {
        gl_lds16(ga[q] + k0, &As[cur ^ 1][dstoff[q]]);
        gl_lds16(gb[q] + k0, &Bs[cur ^ 1][dstoff[q]]);
      }
    }
    #pragma unroll
    for (int kk = 0; kk < BK; kk += 32) {
      s16x8 a[4], b[4];
      #pragma unroll
      for (int i = 0; i < 4; ++i)
        a[i] = *(const s16x8*)(&As[cur][(wr * 64 + i * 16 + fr) * BK + ((kk + q8) ^ rsw)]);
      #pragma unroll
      for (int j = 0; j < 4; ++j)
        b[j] = *(const s16x8*)(&Bs[cur][(wc * 64 + j * 16 + fr) * BK + ((kk + q8) ^ rsw)]);
      #pragma unroll
      for (int i = 0; i < 4; ++i)
        #pragma unroll
        for (int j = 0; j < 4; ++j)
          acc[i][j] = __builtin_amdgcn_mfma_f32_16x16x32_bf16(a[i], b[j], acc[i][j], 0, 0, 0);
    }
    cur ^= 1;
  }

  // epilogue: bias + SwiGLU (pair even/odd N via shfl_xor 1) -> bf16 hact
  const float* bias_e = gu_bias + (size_t)e * N_GU;
  int rbase = m0 + wr * 64 + ((lane >> 4) * 4);
  #pragma unroll
  for (int i = 0; i < 4; ++i) {
    #pragma unroll
    for (int j = 0; j < 4; ++j) {
      int n = n0 + wc * 64 + j * 16 + fr;
      float v[4], o[4];
      #pragma unroll
      for (int r = 0; r < 4; ++r) v[r] = acc[i][j][r] + bias_e[n];
      #pragma unroll
      for (int r = 0; r < 4; ++r) o[r] = __shfl_xor(v[r], 1);
      if ((lane & 1) == 0) {
        int outc = n >> 1;
        #pragma unroll
        for (int r = 0; r < 4; ++r) {
          int pos = rbase + i * 16 + r;
          if (pos < mEnd) {
            float g = v[r], u = o[r];
            float gc = fminf(fmaxf(g, -7.f), 7.f);
            float uc = fminf(fmaxf(u, -7.f), 7.f);
            float sig = 1.f / (1.f + __expf(-1.702f * g));
            float act = gc * sig * (uc + 1.f);
            hact[(size_t)pos * NH + outc] = f2bf(act);
          }
        }
      }
    }
  }
}

// ---------------- grouped GEMM 2: hact @ down_w[e]^T ----------------
__global__ __launch_bounds__(256) void gemm_down(
    const unsigned short* __restrict__ hact,
    const unsigned short* __restrict__ dwb,
    const int* __restrict__ tilemeta,
    float* __restrict__ y) {
  __shared__ __align__(16) short As[2][BM * BK];
  __shared__ __align__(16) short Bs[2][BN * BK];
  int wg = xcd_swz(blockIdx.x, gridDim.x);
  int tileid = wg >> 3;          // y = wg & 7 fast axis
  int n0 = (wg & 7) * BN;
  int nt = tilemeta[0];
  if (tileid >= nt) return;
  int e    = tilemeta[1 + tileid * 3 + 0];
  int m0   = tilemeta[1 + tileid * 3 + 1];
  int mEnd = tilemeta[1 + tileid * 3 + 2];

  int t = threadIdx.x;
  int lane = t & 63;
  int wid = t >> 6;
  int wr = wid >> 1, wc = wid & 1;

  int srow = lane >> 3;
  int scol = (((lane & 7) ^ (srow & 7)) * 8);
  const unsigned short* ga[4];
  const unsigned short* gb[4];
  int dstoff[4];
  #pragma unroll
  for (int q = 0; q < 4; ++q) {
    int rt = wid * 32 + q * 8 + srow;
    int ai = m0 + rt; if (ai >= mEnd) ai = mEnd - 1;
    ga[q] = hact + (size_t)ai * NH + scol;
    gb[q] = dwb + ((size_t)e * EMB + n0 + rt) * NH + scol;
    dstoff[q] = (wid * 32 + q * 8) * BK;
  }

  int fr = lane & 15;
  int q8 = (lane >> 4) * 8;
  int rsw = (fr & 7) << 3;

  f32x4 acc[4][4];
  #pragma unroll
  for (int i = 0; i < 4; ++i)
    #pragma unroll
    for (int j = 0; j < 4; ++j) acc[i][j] = (f32x4){0.f, 0.f, 0.f, 0.f};

  #pragma unroll
  for (int q = 0; q < 4; ++q) {
    gl_lds16(ga[q], &As[0][dstoff[q]]);
    gl_lds16(gb[q], &Bs[0][dstoff[q]]);
  }

  int cur = 0;
  for (int tk = 0; tk < KTILES; ++tk) {
    __syncthreads();
    if (tk + 1 < KTILES) {
      int k0 = (tk + 1) * BK;
      #pragma unroll
      for (int q = 0; q < 4; ++q) {
        gl_lds16(ga[q] + k0, &As[cur ^ 1][dstoff[q]]);
        gl_lds16(gb[q] + k0, &Bs[cur ^ 1][dstoff[q]]);
      }
    }
    #pragma unroll
    for (int kk = 0; kk < BK; kk += 32) {
      s16x8 a[4], b[4];
      #pragma unroll
      for (int i = 0; i < 4; ++i)
        a[i] = *(const s16x8*)(&As[cur][(wr * 64 + i * 16 + fr) * BK + ((kk + q8) ^ rsw)]);
      #pragma unroll
      for (int j = 0; j < 4; ++j)
        b[j] = *(const s16x8*)(&Bs[cur][(wc * 64 + j * 16 + fr) * BK + ((kk + q8) ^ rsw)]);
      #pragma unroll
      for (int i = 0; i < 4; ++i)
        #pragma unroll
        for (int j = 0; j < 4; ++j)
          acc[i][j] = __builtin_amdgcn_mfma_f32_16x16x32_bf16(a[i], b[j], acc[i][j], 0, 0, 0);
    }
    cur ^= 1;
  }

  int rbase = m0 + wr * 64 + ((lane >> 4) * 4);
  #pragma unroll
  for (int i = 0; i < 4; ++i) {
    #pragma unroll
    for (int j = 0; j < 4; ++j) {
      int n = n0 + wc * 64 + j * 16 + fr;
      #pragma unroll
      for (int r = 0; r < 4; ++r) {
        int pos = rbase + i * 16 + r;
        if (pos < mEnd) y[(size_t)pos * EMB + n] = acc[i][j][r];
      }
    }
  }
}

// ---------------- final combine ----------------
__global__ void combine_out(const float* __restrict__ y, const float* __restrict__ down_b,
                            const int* __restrict__ tokE, const float* __restrict__ tokW,
                            const int* __restrict__ apos, float* __restrict__ out, int T) {
  int i = blockIdx.x * blockDim.x + threadIdx.x;
  int tot = T * (EMB / 4);
  if (i >= tot) return;
  int tok = i >> 8;
  int c = i & 255;
  int e0 = tokE[tok * 2], e1 = tokE[tok * 2 + 1];
  float w0 = tokW[tok * 2], w1 = tokW[tok * 2 + 1];
  int p0 = apos[tok * 2], p1 = apos[tok * 2 + 1];
  float4 y0 = ((const float4*)(y + (size_t)p0 * EMB))[c];
  float4 y1 = ((const float4*)(y + (size_t)p1 * EMB))[c];
  float4 b0 = ((const float4*)(down_b + (size_t)e0 * EMB))[c];
  float4 b1 = ((const float4*)(down_b + (size_t)e1 * EMB))[c];
  float4 o;
  o.x = w0 * (y0.x + b0.x) + w1 * (y1.x + b1.x);
  o.y = w0 * (y0.y + b0.y) + w1 * (y1.y + b1.y);
  o.z = w0 * (y0.z + b0.z) + w1 * (y1.z + b1.z);
  o.w = w0 * (y0.w + b0.w) + w1 * (y1.w + b1.w);
  ((float4*)out)[i] = o;
}

extern "C" void kernel_launch(void* const* d_in, const int* in_sizes, int n_in,
                              void* d_out, int out_size, void* d_ws, size_t ws_size,
                              hipStream_t stream) {
  const float* x   = (const float*)d_in[0];
  const float* rw  = (const float*)d_in[1];
  const float* rb  = (const float*)d_in[2];
  const float* guw = (const float*)d_in[3];
  const float* gub = (const float*)d_in[4];
  const float* dw  = (const float*)d_in[5];
  const float* db  = (const float*)d_in[6];
  float* out = (float*)d_out;

  int T = in_sizes[0] / EMB;   // 4096
  int A = T * TOPK;            // 8192

  char* ws = (char*)d_ws;
  size_t off = 0;
  auto alloc = [&](size_t bytes) -> void* {
    void* p = ws + off;
    off = (off + bytes + 255) & ~((size_t)255);
    return p;
  };
  unsigned short* xb   = (unsigned short*)alloc((size_t)T * EMB * 2);
  unsigned short* guwb = (unsigned short*)alloc((size_t)NEXP * N_GU * EMB * 2);
  unsigned short* dwb  = (unsigned short*)alloc((size_t)NEXP * EMB * NH * 2);
  unsigned short* hact = (unsigned short*)alloc((size_t)A * NH * 2);
  float* y             = (float*)alloc((size_t)A * EMB * 4);
  int*   tokE    = (int*)alloc((size_t)A * 4);
  float* tokW    = (float*)alloc((size_t)A * 4);
  int*   apos    = (int*)alloc((size_t)A * 4);
  int*   rowsArr = (int*)alloc((size_t)A * 4);
  int*   fill    = (int*)alloc(NEXP * 4);
  int*   offsets = (int*)alloc((NEXP + 1) * 4);
  int*   tilemeta= (int*)alloc((1 + MAXTILES * 3) * 4);

  hipMemsetAsync(fill, 0, NEXP * 4, stream);

  int n4x = T * EMB / 4;
  int n4g = NEXP * N_GU * EMB / 4;
  int n4d = NEXP * EMB * NH / 4;
  convert_all<<<2048, 256, 0, stream>>>(x, xb, n4x, guw, guwb, n4g, dw, dwb, n4d);

  router_topk<<<T / 4, 256, 0, stream>>>(x, rw, rb, T, tokE, tokW);
  count_meta<<<1, 1024, 0, stream>>>(tokE, A, offsets, tilemeta);
  scatter_tokens<<<A / 256, 256, 0, stream>>>(tokE, offsets, fill, rowsArr, apos, A);

  gemm_gate_up<<<MAXTILES * (N_GU / BN), 256, 0, stream>>>(xb, guwb, gub, rowsArr, tilemeta, hact);
  gemm_down<<<MAXTILES * (EMB / BN), 256, 0, stream>>>(hact, dwb, tilemeta, y);

  combine_out<<<(T * EMB / 4 + 255) / 256, 256, 0, stream>>>(y, db, tokE, tokW, apos, out, T);
}

// Round 5
// 187.154 us; speedup vs baseline: 1.6447x; 1.0234x over previous
//
#include <hip/hip_runtime.h>
#include <hip/hip_bf16.h>

#define EMB 1024
#define NEXP 8
#define NH 1024
#define N_GU 2048
#define TOPK 2

#define BM 128
#define BN 128
#define BK 64
#define KTILES 16      // 1024 / 64
#define MAXTILES 72

typedef __attribute__((ext_vector_type(4))) float f32x4;
typedef __attribute__((ext_vector_type(8))) short s16x8;
typedef __attribute__((ext_vector_type(4))) short s16x4;

typedef __attribute__((address_space(3))) unsigned int lds_u32;
typedef __attribute__((address_space(1))) const unsigned int glb_u32;

__device__ __forceinline__ void gl_lds16(const void* g, void* l) {
  __builtin_amdgcn_global_load_lds((glb_u32*)g, (lds_u32*)l, 16, 0, 0);
}

// raw barrier with compile-time memory fences (no runtime vmcnt drain)
__device__ __forceinline__ void barrier_fence() {
  asm volatile("" ::: "memory");
  __builtin_amdgcn_s_barrier();
  asm volatile("" ::: "memory");
}

__device__ __forceinline__ unsigned short f2bf(float f) {
  union { float f; unsigned int u; } a; a.f = f;
  unsigned int u = a.u;
  unsigned int r = (u + 0x7FFFu + ((u >> 16) & 1u)) >> 16;
  return (unsigned short)r;
}

// bijective chunked XCD swizzle (m204)
__device__ __forceinline__ int xcd_swz(int bid, int nwg) {
  int q = nwg >> 3, r = nwg & 7;
  int xcd = bid & 7, pos = bid >> 3;
  int base = (xcd < r) ? xcd * (q + 1) : r * (q + 1) + (xcd - r) * q;
  return base + pos;
}

// ---------------- fused fp32 -> bf16 conversion ----------------
__global__ void convert_all(const float* __restrict__ a, unsigned short* __restrict__ oa, int n4a,
                            const float* __restrict__ b, unsigned short* __restrict__ ob, int n4b,
                            const float* __restrict__ c, unsigned short* __restrict__ oc, int n4c) {
  int tot = n4a + n4b + n4c;
  for (int i = blockIdx.x * blockDim.x + threadIdx.x; i < tot; i += gridDim.x * blockDim.x) {
    const float* src; unsigned short* dst; int k;
    if (i < n4a) { src = a; dst = oa; k = i; }
    else if (i < n4a + n4b) { src = b; dst = ob; k = i - n4a; }
    else { src = c; dst = oc; k = i - n4a - n4b; }
    float4 v = ((const float4*)src)[k];
    s16x4 o;
    o[0] = (short)f2bf(v.x);
    o[1] = (short)f2bf(v.y);
    o[2] = (short)f2bf(v.z);
    o[3] = (short)f2bf(v.w);
    ((s16x4*)dst)[k] = o;
  }
}

// ---------------- router ----------------
__global__ void router_topk(const float* __restrict__ x, const float* __restrict__ rw,
                            const float* __restrict__ rb, int T,
                            int* __restrict__ tokE, float* __restrict__ tokW) {
  int gwid = (blockIdx.x * blockDim.x + threadIdx.x) >> 6;
  int lane = threadIdx.x & 63;
  if (gwid >= T) return;
  const float* h = x + (size_t)gwid * EMB;
  float hreg[16];
  #pragma unroll
  for (int i = 0; i < 16; ++i) hreg[i] = h[lane + 64 * i];
  float sc[NEXP];
  #pragma unroll
  for (int e = 0; e < NEXP; ++e) {
    const float* w = rw + e * EMB;
    float s = 0.f;
    #pragma unroll
    for (int i = 0; i < 16; ++i) s += hreg[i] * w[lane + 64 * i];
    #pragma unroll
    for (int off = 32; off > 0; off >>= 1) s += __shfl_xor(s, off);
    sc[e] = s + rb[e];
  }
  if (lane == 0) {
    int e0 = 0; float v0 = sc[0];
    #pragma unroll
    for (int e = 1; e < NEXP; ++e) if (sc[e] > v0) { v0 = sc[e]; e0 = e; }
    int e1 = -1; float v1 = -3.0e38f;
    #pragma unroll
    for (int e = 0; e < NEXP; ++e) { if (e == e0) continue; if (sc[e] > v1) { v1 = sc[e]; e1 = e; } }
    float ex = __expf(v1 - v0);
    float w0 = 1.f / (1.f + ex);
    float w1 = ex / (1.f + ex);
    tokE[gwid * 2] = e0; tokE[gwid * 2 + 1] = e1;
    tokW[gwid * 2] = w0; tokW[gwid * 2 + 1] = w1;
  }
}

// ---------------- histogram + offsets + tile map ----------------
__global__ void count_meta(const int* __restrict__ tokE, int A,
                           int* __restrict__ offsets, int* __restrict__ tilemeta) {
  __shared__ int hist[NEXP];
  int t = threadIdx.x;
  if (t < NEXP) hist[t] = 0;
  __syncthreads();
  for (int i = t; i < A; i += blockDim.x) atomicAdd(&hist[tokE[i]], 1);
  __syncthreads();
  if (t == 0) {
    int off = 0, nt = 0;
    for (int e = 0; e < NEXP; ++e) {
      offsets[e] = off;
      int c = hist[e];
      int ntile = (c + BM - 1) / BM;
      for (int k = 0; k < ntile; ++k) {
        tilemeta[1 + nt * 3 + 0] = e;
        tilemeta[1 + nt * 3 + 1] = off + k * BM;
        tilemeta[1 + nt * 3 + 2] = off + c;
        nt++;
      }
      off += c;
    }
    offsets[NEXP] = off;
    tilemeta[0] = nt;
  }
}

// ---------------- scatter with wave-aggregated atomics ----------------
__global__ void scatter_tokens(const int* __restrict__ tokE, const int* __restrict__ offsets,
                               int* __restrict__ fill, int* __restrict__ rows,
                               int* __restrict__ apos, int A) {
  int i = blockIdx.x * blockDim.x + threadIdx.x;
  int lane = threadIdx.x & 63;
  int e = tokE[i];
  int p = -1;
  #pragma unroll
  for (int ex = 0; ex < NEXP; ++ex) {
    unsigned long long mask = __ballot(e == ex);
    if (mask) {
      int leader = __ffsll(mask) - 1;
      int cnt = __popcll(mask);
      int base = 0;
      if (lane == leader) base = atomicAdd(&fill[ex], cnt);
      base = __shfl(base, leader);
      if (e == ex) {
        int rank = __popcll(mask & ((1ull << lane) - 1ull));
        p = offsets[ex] + base + rank;
      }
    }
  }
  rows[p] = i >> 1;
  apos[i] = p;
}

// ---------------- grouped GEMM 1: gathered x @ gate_up_w[e]^T, fused SwiGLU ----------------
__global__ __launch_bounds__(256) void gemm_gate_up(
    const unsigned short* __restrict__ xb,
    const unsigned short* __restrict__ gub,
    const float* __restrict__ gu_bias,
    const int* __restrict__ rows,
    const int* __restrict__ tilemeta,
    unsigned short* __restrict__ hact) {
  __shared__ __align__(16) short As[2][BM * BK];
  __shared__ __align__(16) short Bs[2][BN * BK];
  int wg = xcd_swz(blockIdx.x, gridDim.x);
  int tileid = wg >> 4;          // y = wg & 15 fast axis
  int n0 = (wg & 15) * BN;
  int nt = tilemeta[0];
  if (tileid >= nt) return;
  int e    = tilemeta[1 + tileid * 3 + 0];
  int m0   = tilemeta[1 + tileid * 3 + 1];
  int mEnd = tilemeta[1 + tileid * 3 + 2];

  int t = threadIdx.x;
  int lane = t & 63;
  int wid = t >> 6;
  int wr = wid >> 1, wc = wid & 1;

  // staging: instr q covers rows wid*32+q*8 .. +8; lane l -> row +(l>>3), LDS chunk (l&7).
  // SOURCE pre-swizzle (rule #21): fetch global chunk (l&7) ^ (row&7).
  int srow = lane >> 3;
  int scol = (((lane & 7) ^ (srow & 7)) * 8);
  const unsigned short* ga[4];
  const unsigned short* gb[4];
  int dstoff[4];
  #pragma unroll
  for (int q = 0; q < 4; ++q) {
    int rt = wid * 32 + q * 8 + srow;
    int ai = m0 + rt; if (ai >= mEnd) ai = mEnd - 1;
    ga[q] = xb + (size_t)rows[ai] * EMB + scol;
    gb[q] = gub + ((size_t)e * N_GU + n0 + rt) * EMB + scol;
    dstoff[q] = (wid * 32 + q * 8) * BK;
  }

  int fr = lane & 15;
  int q8 = (lane >> 4) * 8;
  int rsw = (fr & 7) << 3;       // read-side swizzle (elem)

  f32x4 acc[4][4];
  #pragma unroll
  for (int i = 0; i < 4; ++i)
    #pragma unroll
    for (int j = 0; j < 4; ++j) acc[i][j] = (f32x4){0.f, 0.f, 0.f, 0.f};

  // prologue: stage tile 0 into buf 0
  #pragma unroll
  for (int q = 0; q < 4; ++q) {
    gl_lds16(ga[q], &As[0][dstoff[q]]);
    gl_lds16(gb[q], &Bs[0][dstoff[q]]);
  }

  for (int tk = 0; tk < KTILES; ++tk) {
    int cur = tk & 1;
    if (tk + 1 < KTILES) {
      int k0 = (tk + 1) * BK;
      #pragma unroll
      for (int q = 0; q < 4; ++q) {
        gl_lds16(ga[q] + k0, &As[cur ^ 1][dstoff[q]]);
        gl_lds16(gb[q] + k0, &Bs[cur ^ 1][dstoff[q]]);
      }
      asm volatile("s_waitcnt vmcnt(8)" ::: "memory");  // tk landed, tk+1 stays in flight
    } else {
      asm volatile("s_waitcnt vmcnt(0)" ::: "memory");
    }
    barrier_fence();   // all waves' tile-tk DMA visible
    #pragma unroll
    for (int kk = 0; kk < BK; kk += 32) {
      s16x8 a[4], b[4];
      #pragma unroll
      for (int i = 0; i < 4; ++i)
        a[i] = *(const s16x8*)(&As[cur][(wr * 64 + i * 16 + fr) * BK + ((kk + q8) ^ rsw)]);
      #pragma unroll
      for (int j = 0; j < 4; ++j)
        b[j] = *(const s16x8*)(&Bs[cur][(wc * 64 + j * 16 + fr) * BK + ((kk + q8) ^ rsw)]);
      #pragma unroll
      for (int i = 0; i < 4; ++i)
        #pragma unroll
        for (int j = 0; j < 4; ++j)
          acc[i][j] = __builtin_amdgcn_mfma_f32_16x16x32_bf16(a[i], b[j], acc[i][j], 0, 0, 0);
    }
    barrier_fence();   // all reads of buf[cur] done before stage(tk+2) overwrites it
  }

  // epilogue: bias + SwiGLU (pair even/odd N via shfl_xor 1) -> bf16 hact
  const float* bias_e = gu_bias + (size_t)e * N_GU;
  int rbase = m0 + wr * 64 + ((lane >> 4) * 4);
  #pragma unroll
  for (int i = 0; i < 4; ++i) {
    #pragma unroll
    for (int j = 0; j < 4; ++j) {
      int n = n0 + wc * 64 + j * 16 + fr;
      float v[4], o[4];
      #pragma unroll
      for (int r = 0; r < 4; ++r) v[r] = acc[i][j][r] + bias_e[n];
      #pragma unroll
      for (int r = 0; r < 4; ++r) o[r] = __shfl_xor(v[r], 1);
      if ((lane & 1) == 0) {
        int outc = n >> 1;
        #pragma unroll
        for (int r = 0; r < 4; ++r) {
          int pos = rbase + i * 16 + r;
          if (pos < mEnd) {
            float g = v[r], u = o[r];
            float gc = fminf(fmaxf(g, -7.f), 7.f);
            float uc = fminf(fmaxf(u, -7.f), 7.f);
            float sig = 1.f / (1.f + __expf(-1.702f * g));
            float act = gc * sig * (uc + 1.f);
            hact[(size_t)pos * NH + outc] = f2bf(act);
          }
        }
      }
    }
  }
}

// ---------------- grouped GEMM 2: hact @ down_w[e]^T ----------------
__global__ __launch_bounds__(256) void gemm_down(
    const unsigned short* __restrict__ hact,
    const unsigned short* __restrict__ dwb,
    const int* __restrict__ tilemeta,
    float* __restrict__ y) {
  __shared__ __align__(16) short As[2][BM * BK];
  __shared__ __align__(16) short Bs[2][BN * BK];
  int wg = xcd_swz(blockIdx.x, gridDim.x);
  int tileid = wg >> 3;          // y = wg & 7 fast axis
  int n0 = (wg & 7) * BN;
  int nt = tilemeta[0];
  if (tileid >= nt) return;
  int e    = tilemeta[1 + tileid * 3 + 0];
  int m0   = tilemeta[1 + tileid * 3 + 1];
  int mEnd = tilemeta[1 + tileid * 3 + 2];

  int t = threadIdx.x;
  int lane = t & 63;
  int wid = t >> 6;
  int wr = wid >> 1, wc = wid & 1;

  int srow = lane >> 3;
  int scol = (((lane & 7) ^ (srow & 7)) * 8);
  const unsigned short* ga[4];
  const unsigned short* gb[4];
  int dstoff[4];
  #pragma unroll
  for (int q = 0; q < 4; ++q) {
    int rt = wid * 32 + q * 8 + srow;
    int ai = m0 + rt; if (ai >= mEnd) ai = mEnd - 1;
    ga[q] = hact + (size_t)ai * NH + scol;
    gb[q] = dwb + ((size_t)e * EMB + n0 + rt) * NH + scol;
    dstoff[q] = (wid * 32 + q * 8) * BK;
  }

  int fr = lane & 15;
  int q8 = (lane >> 4) * 8;
  int rsw = (fr & 7) << 3;

  f32x4 acc[4][4];
  #pragma unroll
  for (int i = 0; i < 4; ++i)
    #pragma unroll
    for (int j = 0; j < 4; ++j) acc[i][j] = (f32x4){0.f, 0.f, 0.f, 0.f};

  #pragma unroll
  for (int q = 0; q < 4; ++q) {
    gl_lds16(ga[q], &As[0][dstoff[q]]);
    gl_lds16(gb[q], &Bs[0][dstoff[q]]);
  }

  for (int tk = 0; tk < KTILES; ++tk) {
    int cur = tk & 1;
    if (tk + 1 < KTILES) {
      int k0 = (tk + 1) * BK;
      #pragma unroll
      for (int q = 0; q < 4; ++q) {
        gl_lds16(ga[q] + k0, &As[cur ^ 1][dstoff[q]]);
        gl_lds16(gb[q] + k0, &Bs[cur ^ 1][dstoff[q]]);
      }
      asm volatile("s_waitcnt vmcnt(8)" ::: "memory");
    } else {
      asm volatile("s_waitcnt vmcnt(0)" ::: "memory");
    }
    barrier_fence();
    #pragma unroll
    for (int kk = 0; kk < BK; kk += 32) {
      s16x8 a[4], b[4];
      #pragma unroll
      for (int i = 0; i < 4; ++i)
        a[i] = *(const s16x8*)(&As[cur][(wr * 64 + i * 16 + fr) * BK + ((kk + q8) ^ rsw)]);
      #pragma unroll
      for (int j = 0; j < 4; ++j)
        b[j] = *(const s16x8*)(&Bs[cur][(wc * 64 + j * 16 + fr) * BK + ((kk + q8) ^ rsw)]);
      #pragma unroll
      for (int i = 0; i < 4; ++i)
        #pragma unroll
        for (int j = 0; j < 4; ++j)
          acc[i][j] = __builtin_amdgcn_mfma_f32_16x16x32_bf16(a[i], b[j], acc[i][j], 0, 0, 0);
    }
    barrier_fence();
  }

  int rbase = m0 + wr * 64 + ((lane >> 4) * 4);
  #pragma unroll
  for (int i = 0; i < 4; ++i) {
    #pragma unroll
    for (int j = 0; j < 4; ++j) {
      int n = n0 + wc * 64 + j * 16 + fr;
      #pragma unroll
      for (int r = 0; r < 4; ++r) {
        int pos = rbase + i * 16 + r;
        if (pos < mEnd) y[(size_t)pos * EMB + n] = acc[i][j][r];
      }
    }
  }
}

// ---------------- final combine ----------------
__global__ void combine_out(const float* __restrict__ y, const float* __restrict__ down_b,
                            const int* __restrict__ tokE, const float* __restrict__ tokW,
                            const int* __restrict__ apos, float* __restrict__ out, int T) {
  int i = blockIdx.x * blockDim.x + threadIdx.x;
  int tot = T * (EMB / 4);
  if (i >= tot) return;
  int tok = i >> 8;
  int c = i & 255;
  int e0 = tokE[tok * 2], e1 = tokE[tok * 2 + 1];
  float w0 = tokW[tok * 2], w1 = tokW[tok * 2 + 1];
  int p0 = apos[tok * 2], p1 = apos[tok * 2 + 1];
  float4 y0 = ((const float4*)(y + (size_t)p0 * EMB))[c];
  float4 y1 = ((const float4*)(y + (size_t)p1 * EMB))[c];
  float4 b0 = ((const float4*)(down_b + (size_t)e0 * EMB))[c];
  float4 b1 = ((const float4*)(down_b + (size_t)e1 * EMB))[c];
  float4 o;
  o.x = w0 * (y0.x + b0.x) + w1 * (y1.x + b1.x);
  o.y = w0 * (y0.y + b0.y) + w1 * (y1.y + b1.y);
  o.z = w0 * (y0.z + b0.z) + w1 * (y1.z + b1.z);
  o.w = w0 * (y0.w + b0.w) + w1 * (y1.w + b1.w);
  ((float4*)out)[i] = o;
}

extern "C" void kernel_launch(void* const* d_in, const int* in_sizes, int n_in,
                              void* d_out, int out_size, void* d_ws, size_t ws_size,
                              hipStream_t stream) {
  const float* x   = (const float*)d_in[0];
  const float* rw  = (const float*)d_in[1];
  const float* rb  = (const float*)d_in[2];
  const float* guw = (const float*)d_in[3];
  const float* gub = (const float*)d_in[4];
  const float* dw  = (const float*)d_in[5];
  const float* db  = (const float*)d_in[6];
  float* out = (float*)d_out;

  int T = in_sizes[0] / EMB;   // 4096
  int A = T * TOPK;            // 8192

  char* ws = (char*)d_ws;
  size_t off = 0;
  auto alloc = [&](size_t bytes) -> void* {
    void* p = ws + off;
    off = (off + bytes + 255) & ~((size_t)255);
    return p;
  };
  unsigned short* xb   = (unsigned short*)alloc((size_t)T * EMB * 2);
  unsigned short* guwb = (unsigned short*)alloc((size_t)NEXP * N_GU * EMB * 2);
  unsigned short* dwb  = (unsigned short*)alloc((size_t)NEXP * EMB * NH * 2);
  unsigned short* hact = (unsigned short*)alloc((size_t)A * NH * 2);
  float* y             = (float*)alloc((size_t)A * EMB * 4);
  int*   tokE    = (int*)alloc((size_t)A * 4);
  float* tokW    = (float*)alloc((size_t)A * 4);
  int*   apos    = (int*)alloc((size_t)A * 4);
  int*   rowsArr = (int*)alloc((size_t)A * 4);
  int*   fill    = (int*)alloc(NEXP * 4);
  int*   offsets = (int*)alloc((NEXP + 1) * 4);
  int*   tilemeta= (int*)alloc((1 + MAXTILES * 3) * 4);

  hipMemsetAsync(fill, 0, NEXP * 4, stream);

  int n4x = T * EMB / 4;
  int n4g = NEXP * N_GU * EMB / 4;
  int n4d = NEXP * EMB * NH / 4;
  convert_all<<<2048, 256, 0, stream>>>(x, xb, n4x, guw, guwb, n4g, dw, dwb, n4d);

  router_topk<<<T / 4, 256, 0, stream>>>(x, rw, rb, T, tokE, tokW);
  count_meta<<<1, 1024, 0, stream>>>(tokE, A, offsets, tilemeta);
  scatter_tokens<<<A / 256, 256, 0, stream>>>(tokE, offsets, fill, rowsArr, apos, A);

  gemm_gate_up<<<MAXTILES * (N_GU / BN), 256, 0, stream>>>(xb, guwb, gub, rowsArr, tilemeta, hact);
  gemm_down<<<MAXTILES * (EMB / BN), 256, 0, stream>>>(hact, dwb, tilemeta, y);

  combine_out<<<(T * EMB / 4 + 255) / 256, 256, 0, stream>>>(y, db, tokE, tokW, apos, out, T);
}

// Round 6
// 159.102 us; speedup vs baseline: 1.9347x; 1.1763x over previous
//
#include <hip/hip_runtime.h>
#include <hip/hip_bf16.h>

#define EMB 1024
#define NEXP 8
#define NH 1024
#define N_GU 2048
#define TOPK 2

#define BM 128
#define BN 128
#define BK 64
#define KTILES 16      // 1024 / 64
#define MAXTILES 72

typedef __attribute__((ext_vector_type(4))) float f32x4;
typedef __attribute__((ext_vector_type(8))) short s16x8;
typedef __attribute__((ext_vector_type(4))) short s16x4;

typedef __attribute__((address_space(3))) unsigned int lds_u32;
typedef __attribute__((address_space(1))) const unsigned int glb_u32;

__device__ __forceinline__ void gl_lds16(const void* g, void* l) {
  __builtin_amdgcn_global_load_lds((glb_u32*)g, (lds_u32*)l, 16, 0, 0);
}

__device__ __forceinline__ unsigned short f2bf(float f) {
  union { float f; unsigned int u; } a; a.f = f;
  unsigned int u = a.u;
  unsigned int r = (u + 0x7FFFu + ((u >> 16) & 1u)) >> 16;
  return (unsigned short)r;
}

// bijective chunked XCD swizzle (m204)
__device__ __forceinline__ int xcd_swz(int bid, int nwg) {
  int q = nwg >> 3, r = nwg & 7;
  int xcd = bid & 7, pos = bid >> 3;
  int base = (xcd < r) ? xcd * (q + 1) : r * (q + 1) + (xcd - r) * q;
  return base + pos;
}

// ---------------- fused fp32 -> bf16 conversion ----------------
__global__ void convert_all(const float* __restrict__ a, unsigned short* __restrict__ oa, int n4a,
                            const float* __restrict__ b, unsigned short* __restrict__ ob, int n4b,
                            const float* __restrict__ c, unsigned short* __restrict__ oc, int n4c) {
  int tot = n4a + n4b + n4c;
  for (int i = blockIdx.x * blockDim.x + threadIdx.x; i < tot; i += gridDim.x * blockDim.x) {
    const float* src; unsigned short* dst; int k;
    if (i < n4a) { src = a; dst = oa; k = i; }
    else if (i < n4a + n4b) { src = b; dst = ob; k = i - n4a; }
    else { src = c; dst = oc; k = i - n4a - n4b; }
    float4 v = ((const float4*)src)[k];
    s16x4 o;
    o[0] = (short)f2bf(v.x);
    o[1] = (short)f2bf(v.y);
    o[2] = (short)f2bf(v.z);
    o[3] = (short)f2bf(v.w);
    ((s16x4*)dst)[k] = o;
  }
}

// ---------------- router ----------------
__global__ void router_topk(const float* __restrict__ x, const float* __restrict__ rw,
                            const float* __restrict__ rb, int T,
                            int* __restrict__ tokE, float* __restrict__ tokW) {
  int gwid = (blockIdx.x * blockDim.x + threadIdx.x) >> 6;
  int lane = threadIdx.x & 63;
  if (gwid >= T) return;
  const float* h = x + (size_t)gwid * EMB;
  float hreg[16];
  #pragma unroll
  for (int i = 0; i < 16; ++i) hreg[i] = h[lane + 64 * i];
  float sc[NEXP];
  #pragma unroll
  for (int e = 0; e < NEXP; ++e) {
    const float* w = rw + e * EMB;
    float s = 0.f;
    #pragma unroll
    for (int i = 0; i < 16; ++i) s += hreg[i] * w[lane + 64 * i];
    #pragma unroll
    for (int off = 32; off > 0; off >>= 1) s += __shfl_xor(s, off);
    sc[e] = s + rb[e];
  }
  if (lane == 0) {
    int e0 = 0; float v0 = sc[0];
    #pragma unroll
    for (int e = 1; e < NEXP; ++e) if (sc[e] > v0) { v0 = sc[e]; e0 = e; }
    int e1 = -1; float v1 = -3.0e38f;
    #pragma unroll
    for (int e = 0; e < NEXP; ++e) { if (e == e0) continue; if (sc[e] > v1) { v1 = sc[e]; e1 = e; } }
    float ex = __expf(v1 - v0);
    float w0 = 1.f / (1.f + ex);
    float w1 = ex / (1.f + ex);
    tokE[gwid * 2] = e0; tokE[gwid * 2 + 1] = e1;
    tokW[gwid * 2] = w0; tokW[gwid * 2 + 1] = w1;
  }
}

// ---------------- histogram + offsets + tile map ----------------
__global__ void count_meta(const int* __restrict__ tokE, int A,
                           int* __restrict__ offsets, int* __restrict__ tilemeta) {
  __shared__ int hist[NEXP];
  int t = threadIdx.x;
  if (t < NEXP) hist[t] = 0;
  __syncthreads();
  for (int i = t; i < A; i += blockDim.x) atomicAdd(&hist[tokE[i]], 1);
  __syncthreads();
  if (t == 0) {
    int off = 0, nt = 0;
    for (int e = 0; e < NEXP; ++e) {
      offsets[e] = off;
      int c = hist[e];
      int ntile = (c + BM - 1) / BM;
      for (int k = 0; k < ntile; ++k) {
        tilemeta[1 + nt * 3 + 0] = e;
        tilemeta[1 + nt * 3 + 1] = off + k * BM;
        tilemeta[1 + nt * 3 + 2] = off + c;
        nt++;
      }
      off += c;
    }
    offsets[NEXP] = off;
    tilemeta[0] = nt;
  }
}

// ---------------- scatter with wave-aggregated atomics ----------------
__global__ void scatter_tokens(const int* __restrict__ tokE, const int* __restrict__ offsets,
                               int* __restrict__ fill, int* __restrict__ rows,
                               int* __restrict__ apos, int A) {
  int i = blockIdx.x * blockDim.x + threadIdx.x;
  int lane = threadIdx.x & 63;
  int e = tokE[i];
  int p = -1;
  #pragma unroll
  for (int ex = 0; ex < NEXP; ++ex) {
    unsigned long long mask = __ballot(e == ex);
    if (mask) {
      int leader = __ffsll(mask) - 1;
      int cnt = __popcll(mask);
      int base = 0;
      if (lane == leader) base = atomicAdd(&fill[ex], cnt);
      base = __shfl(base, leader);
      if (e == ex) {
        int rank = __popcll(mask & ((1ull << lane) - 1ull));
        p = offsets[ex] + base + rank;
      }
    }
  }
  rows[p] = i >> 1;
  apos[i] = p;
}

// ---------------- grouped GEMM 1: gathered x @ gate_up_w[e]^T, fused SwiGLU ----------------
// single-buffer 32KB LDS -> ~5 blocks/CU; cross-block overlap hides stage drain (m97/m114)
__global__ __launch_bounds__(256, 4) void gemm_gate_up(
    const unsigned short* __restrict__ xb,
    const unsigned short* __restrict__ gub,
    const float* __restrict__ gu_bias,
    const int* __restrict__ rows,
    const int* __restrict__ tilemeta,
    unsigned short* __restrict__ hact) {
  __shared__ __align__(16) short As[BM * BK];
  __shared__ __align__(16) short Bs[BN * BK];
  int wg = xcd_swz(blockIdx.x, gridDim.x);
  int tileid = wg >> 4;          // y = wg & 15 fast axis (A-tile reuse adjacency)
  int n0 = (wg & 15) * BN;
  int nt = tilemeta[0];
  if (tileid >= nt) return;
  int e    = tilemeta[1 + tileid * 3 + 0];
  int m0   = tilemeta[1 + tileid * 3 + 1];
  int mEnd = tilemeta[1 + tileid * 3 + 2];

  int t = threadIdx.x;
  int lane = t & 63;
  int wid = t >> 6;
  int wr = wid >> 1, wc = wid & 1;

  // staging: inst q covers rows wid*32+q*8..+8; lane l -> row +(l>>3), LDS chunk (l&7).
  // SOURCE pre-swizzle (rule #21): fetch global chunk (l&7) ^ (row&7).
  int srow = lane >> 3;
  int scol = (((lane & 7) ^ (srow & 7)) * 8);
  const unsigned short* ga[4];
  const unsigned short* gb[4];
  int dstoff[4];
  #pragma unroll
  for (int q = 0; q < 4; ++q) {
    int rt = wid * 32 + q * 8 + srow;
    int ai = m0 + rt; if (ai >= mEnd) ai = mEnd - 1;
    ga[q] = xb + (size_t)rows[ai] * EMB + scol;
    gb[q] = gub + ((size_t)e * N_GU + n0 + rt) * EMB + scol;
    dstoff[q] = (wid * 32 + q * 8) * BK;
  }

  int fr = lane & 15;
  int q8 = (lane >> 4) * 8;
  int rsw = (fr & 7) << 3;       // read-side swizzle (elem), row&7 = fr&7

  f32x4 acc[4][4];
  #pragma unroll
  for (int i = 0; i < 4; ++i)
    #pragma unroll
    for (int j = 0; j < 4; ++j) acc[i][j] = (f32x4){0.f, 0.f, 0.f, 0.f};

  for (int tk = 0; tk < KTILES; ++tk) {
    int k0 = tk * BK;
    __syncthreads();             // buffer free (previous compute done)
    #pragma unroll
    for (int q = 0; q < 4; ++q) {
      gl_lds16(ga[q] + k0, &As[dstoff[q]]);
      gl_lds16(gb[q] + k0, &Bs[dstoff[q]]);
    }
    __syncthreads();             // implicit vmcnt(0) drain: tile visible to all waves
    #pragma unroll
    for (int kk = 0; kk < BK; kk += 32) {
      s16x8 a[4], b[4];
      #pragma unroll
      for (int i = 0; i < 4; ++i)
        a[i] = *(const s16x8*)(&As[(wr * 64 + i * 16 + fr) * BK + ((kk + q8) ^ rsw)]);
      #pragma unroll
      for (int j = 0; j < 4; ++j)
        b[j] = *(const s16x8*)(&Bs[(wc * 64 + j * 16 + fr) * BK + ((kk + q8) ^ rsw)]);
      #pragma unroll
      for (int i = 0; i < 4; ++i)
        #pragma unroll
        for (int j = 0; j < 4; ++j)
          acc[i][j] = __builtin_amdgcn_mfma_f32_16x16x32_bf16(a[i], b[j], acc[i][j], 0, 0, 0);
    }
  }

  // epilogue: bias + SwiGLU (pair even/odd N via shfl_xor 1) -> bf16 hact
  const float* bias_e = gu_bias + (size_t)e * N_GU;
  int rbase = m0 + wr * 64 + ((lane >> 4) * 4);
  #pragma unroll
  for (int i = 0; i < 4; ++i) {
    #pragma unroll
    for (int j = 0; j < 4; ++j) {
      int n = n0 + wc * 64 + j * 16 + fr;
      float v[4], o[4];
      #pragma unroll
      for (int r = 0; r < 4; ++r) v[r] = acc[i][j][r] + bias_e[n];
      #pragma unroll
      for (int r = 0; r < 4; ++r) o[r] = __shfl_xor(v[r], 1);
      if ((lane & 1) == 0) {
        int outc = n >> 1;
        #pragma unroll
        for (int r = 0; r < 4; ++r) {
          int pos = rbase + i * 16 + r;
          if (pos < mEnd) {
            float g = v[r], u = o[r];
            float gc = fminf(fmaxf(g, -7.f), 7.f);
            float uc = fminf(fmaxf(u, -7.f), 7.f);
            float sig = 1.f / (1.f + __expf(-1.702f * g));
            float act = gc * sig * (uc + 1.f);
            hact[(size_t)pos * NH + outc] = f2bf(act);
          }
        }
      }
    }
  }
}

// ---------------- grouped GEMM 2: hact @ down_w[e]^T ----------------
__global__ __launch_bounds__(256, 4) void gemm_down(
    const unsigned short* __restrict__ hact,
    const unsigned short* __restrict__ dwb,
    const int* __restrict__ tilemeta,
    float* __restrict__ y) {
  __shared__ __align__(16) short As[BM * BK];
  __shared__ __align__(16) short Bs[BN * BK];
  int wg = xcd_swz(blockIdx.x, gridDim.x);
  int tileid = wg >> 3;          // y = wg & 7 fast axis
  int n0 = (wg & 7) * BN;
  int nt = tilemeta[0];
  if (tileid >= nt) return;
  int e    = tilemeta[1 + tileid * 3 + 0];
  int m0   = tilemeta[1 + tileid * 3 + 1];
  int mEnd = tilemeta[1 + tileid * 3 + 2];

  int t = threadIdx.x;
  int lane = t & 63;
  int wid = t >> 6;
  int wr = wid >> 1, wc = wid & 1;

  int srow = lane >> 3;
  int scol = (((lane & 7) ^ (srow & 7)) * 8);
  const unsigned short* ga[4];
  const unsigned short* gb[4];
  int dstoff[4];
  #pragma unroll
  for (int q = 0; q < 4; ++q) {
    int rt = wid * 32 + q * 8 + srow;
    int ai = m0 + rt; if (ai >= mEnd) ai = mEnd - 1;
    ga[q] = hact + (size_t)ai * NH + scol;
    gb[q] = dwb + ((size_t)e * EMB + n0 + rt) * NH + scol;
    dstoff[q] = (wid * 32 + q * 8) * BK;
  }

  int fr = lane & 15;
  int q8 = (lane >> 4) * 8;
  int rsw = (fr & 7) << 3;

  f32x4 acc[4][4];
  #pragma unroll
  for (int i = 0; i < 4; ++i)
    #pragma unroll
    for (int j = 0; j < 4; ++j) acc[i][j] = (f32x4){0.f, 0.f, 0.f, 0.f};

  for (int tk = 0; tk < KTILES; ++tk) {
    int k0 = tk * BK;
    __syncthreads();
    #pragma unroll
    for (int q = 0; q < 4; ++q) {
      gl_lds16(ga[q] + k0, &As[dstoff[q]]);
      gl_lds16(gb[q] + k0, &Bs[dstoff[q]]);
    }
    __syncthreads();
    #pragma unroll
    for (int kk = 0; kk < BK; kk += 32) {
      s16x8 a[4], b[4];
      #pragma unroll
      for (int i = 0; i < 4; ++i)
        a[i] = *(const s16x8*)(&As[(wr * 64 + i * 16 + fr) * BK + ((kk + q8) ^ rsw)]);
      #pragma unroll
      for (int j = 0; j < 4; ++j)
        b[j] = *(const s16x8*)(&Bs[(wc * 64 + j * 16 + fr) * BK + ((kk + q8) ^ rsw)]);
      #pragma unroll
      for (int i = 0; i < 4; ++i)
        #pragma unroll
        for (int j = 0; j < 4; ++j)
          acc[i][j] = __builtin_amdgcn_mfma_f32_16x16x32_bf16(a[i], b[j], acc[i][j], 0, 0, 0);
    }
  }

  int rbase = m0 + wr * 64 + ((lane >> 4) * 4);
  #pragma unroll
  for (int i = 0; i < 4; ++i) {
    #pragma unroll
    for (int j = 0; j < 4; ++j) {
      int n = n0 + wc * 64 + j * 16 + fr;
      #pragma unroll
      for (int r = 0; r < 4; ++r) {
        int pos = rbase + i * 16 + r;
        if (pos < mEnd) y[(size_t)pos * EMB + n] = acc[i][j][r];
      }
    }
  }
}

// ---------------- final combine ----------------
__global__ void combine_out(const float* __restrict__ y, const float* __restrict__ down_b,
                            const int* __restrict__ tokE, const float* __restrict__ tokW,
                            const int* __restrict__ apos, float* __restrict__ out, int T) {
  int i = blockIdx.x * blockDim.x + threadIdx.x;
  int tot = T * (EMB / 4);
  if (i >= tot) return;
  int tok = i >> 8;
  int c = i & 255;
  int e0 = tokE[tok * 2], e1 = tokE[tok * 2 + 1];
  float w0 = tokW[tok * 2], w1 = tokW[tok * 2 + 1];
  int p0 = apos[tok * 2], p1 = apos[tok * 2 + 1];
  float4 y0 = ((const float4*)(y + (size_t)p0 * EMB))[c];
  float4 y1 = ((const float4*)(y + (size_t)p1 * EMB))[c];
  float4 b0 = ((const float4*)(down_b + (size_t)e0 * EMB))[c];
  float4 b1 = ((const float4*)(down_b + (size_t)e1 * EMB))[c];
  float4 o;
  o.x = w0 * (y0.x + b0.x) + w1 * (y1.x + b1.x);
  o.y = w0 * (y0.y + b0.y) + w1 * (y1.y + b1.y);
  o.z = w0 * (y0.z + b0.z) + w1 * (y1.z + b1.z);
  o.w = w0 * (y0.w + b0.w) + w1 * (y1.w + b1.w);
  ((float4*)out)[i] = o;
}

extern "C" void kernel_launch(void* const* d_in, const int* in_sizes, int n_in,
                              void* d_out, int out_size, void* d_ws, size_t ws_size,
                              hipStream_t stream) {
  const float* x   = (const float*)d_in[0];
  const float* rw  = (const float*)d_in[1];
  const float* rb  = (const float*)d_in[2];
  const float* guw = (const float*)d_in[3];
  const float* gub = (const float*)d_in[4];
  const float* dw  = (const float*)d_in[5];
  const float* db  = (const float*)d_in[6];
  float* out = (float*)d_out;

  int T = in_sizes[0] / EMB;   // 4096
  int A = T * TOPK;            // 8192

  char* ws = (char*)d_ws;
  size_t off = 0;
  auto alloc = [&](size_t bytes) -> void* {
    void* p = ws + off;
    off = (off + bytes + 255) & ~((size_t)255);
    return p;
  };
  unsigned short* xb   = (unsigned short*)alloc((size_t)T * EMB * 2);
  unsigned short* guwb = (unsigned short*)alloc((size_t)NEXP * N_GU * EMB * 2);
  unsigned short* dwb  = (unsigned short*)alloc((size_t)NEXP * EMB * NH * 2);
  unsigned short* hact = (unsigned short*)alloc((size_t)A * NH * 2);
  float* y             = (float*)alloc((size_t)A * EMB * 4);
  int*   tokE    = (int*)alloc((size_t)A * 4);
  float* tokW    = (float*)alloc((size_t)A * 4);
  int*   apos    = (int*)alloc((size_t)A * 4);
  int*   rowsArr = (int*)alloc((size_t)A * 4);
  int*   fill    = (int*)alloc(NEXP * 4);
  int*   offsets = (int*)alloc((NEXP + 1) * 4);
  int*   tilemeta= (int*)alloc((1 + MAXTILES * 3) * 4);

  hipMemsetAsync(fill, 0, NEXP * 4, stream);

  int n4x = T * EMB / 4;
  int n4g = NEXP * N_GU * EMB / 4;
  int n4d = NEXP * EMB * NH / 4;
  convert_all<<<2048, 256, 0, stream>>>(x, xb, n4x, guw, guwb, n4g, dw, dwb, n4d);

  router_topk<<<T / 4, 256, 0, stream>>>(x, rw, rb, T, tokE, tokW);
  count_meta<<<1, 1024, 0, stream>>>(tokE, A, offsets, tilemeta);
  scatter_tokens<<<A / 256, 256, 0, stream>>>(tokE, offsets, fill, rowsArr, apos, A);

  gemm_gate_up<<<MAXTILES * (N_GU / BN), 256, 0, stream>>>(xb, guwb, gub, rowsArr, tilemeta, hact);
  gemm_down<<<MAXTILES * (EMB / BN), 256, 0, stream>>>(hact, dwb, tilemeta, y);

  combine_out<<<(T * EMB / 4 + 255) / 256, 256, 0, stream>>>(y, db, tokE, tokW, apos, out, T);
}